// Round 8
// baseline (147.591 us; speedup 1.0000x reference)
//
#include <hip/hip_runtime.h>
#include <math.h>

#define N_ 4
#define L_ 2048
#define E_ 512
#define H_ 8
#define D_ 64

// SCALE = 1/sqrt(512) (reference scales by sqrt(embed_size));
// QSCALE = SCALE * log2(e): scores come out of QK^T in log2 domain.
#define QSCALE 0.06375871588055019f

typedef short s16x8 __attribute__((ext_vector_type(8)));
typedef float f32x4 __attribute__((ext_vector_type(4)));
typedef float f32x16 __attribute__((ext_vector_type(16)));
typedef unsigned int u32x4 __attribute__((ext_vector_type(4)));

typedef const __attribute__((address_space(1))) unsigned int ga_u32;
typedef __attribute__((address_space(3))) unsigned int lds_u32;

// async 16B global->LDS (dest = wave-uniform base + lane*16, linear)
__device__ __forceinline__ void gl_lds16(const unsigned short* g, unsigned short* l) {
    __builtin_amdgcn_global_load_lds((ga_u32*)g, (lds_u32*)l, 16, 0, 0);
}
__device__ __forceinline__ float exp2a(float x) {
    float r; asm("v_exp_f32 %0, %1" : "=v"(r) : "v"(x)); return r;
}
__device__ __forceinline__ unsigned int cvtpk(float lo, float hi) {
    unsigned int r; asm("v_cvt_pk_bf16_f32 %0, %1, %2" : "=v"(r) : "v"(lo), "v"(hi)); return r;
}
// v_permlane32_swap_b32 a, b: a<-{a_lo, b_lo}, b<-{a_hi, b_hi} (lane halves)
__device__ __forceinline__ void swap32(unsigned int& a, unsigned int& b) {
    asm volatile("v_permlane32_swap_b32 %0, %1" : "+v"(a), "+v"(b));
}
__device__ __forceinline__ float max3f(float a, float b, float c) {
    return fmaxf(fmaxf(a, b), c);   // clang fuses to v_max3_f32
}
__device__ __forceinline__ unsigned short f2bf(float x) {
    unsigned int u = __builtin_bit_cast(unsigned int, x);
    u = (u + 0x7FFFu + ((u >> 16) & 1u)) >> 16;   // RNE
    return (unsigned short)u;
}
__device__ __forceinline__ float bflo(unsigned int w) {
    return __builtin_bit_cast(float, w << 16);
}
__device__ __forceinline__ float bfhi(unsigned int w) {
    return __builtin_bit_cast(float, w & 0xFFFF0000u);
}

// ---------------------------------------------------------------------------
// Kernel 0: split Wo (fp32 512x512) into bf16 hi + bf16 residual lo.
// ---------------------------------------------------------------------------
__global__ __launch_bounds__(256) void wo_split_kernel(
    const float* __restrict__ Wo, unsigned short* __restrict__ Whi,
    unsigned short* __restrict__ Wlo)
{
    const int i = blockIdx.x * 256 + threadIdx.x;
    const float4 w = reinterpret_cast<const float4*>(Wo)[i];
    const unsigned int hxy = cvtpk(w.x, w.y);
    const unsigned int hzw = cvtpk(w.z, w.w);
    const unsigned int lxy = cvtpk(w.x - bflo(hxy), w.y - bfhi(hxy));
    const unsigned int lzw = cvtpk(w.z - bflo(hzw), w.w - bfhi(hzw));
    uint2 hh; hh.x = hxy; hh.y = hzw;
    uint2 ll; ll.x = lxy; ll.y = lzw;
    reinterpret_cast<uint2*>(Whi)[i] = hh;
    reinterpret_cast<uint2*>(Wlo)[i] = ll;
}

// ---------------------------------------------------------------------------
// Kernel 1: per-head QKV projection (fp32 compute, bf16 output).
// Q pre-scaled by QSCALE. Qp/Kp: [nh][l][d]; Vt: [nh][d][l].
// ---------------------------------------------------------------------------
__global__ __launch_bounds__(256) void qkv_proj_kernel(
    const float* __restrict__ Q, const float* __restrict__ K, const float* __restrict__ V,
    const float* __restrict__ Wq, const float* __restrict__ Wk, const float* __restrict__ Wv,
    unsigned short* __restrict__ Qp, unsigned short* __restrict__ Kp,
    unsigned short* __restrict__ Vt)
{
    __shared__ float Xl[64][68];
    __shared__ float Wl[64][68];
    __shared__ __align__(16) unsigned short Yl[64][72];

    const int tid = threadIdx.x;
    const int lt = blockIdx.x;
    const int nh = blockIdx.y;
    const int m  = blockIdx.z;       // 0:Q 1:K 2:V
    const int n = nh >> 3, h = nh & 7;
    const int l0 = lt * 64;

    const float* __restrict__ in = (m == 0) ? Q : (m == 1) ? K : V;
    const float* __restrict__ W  = (m == 0) ? Wq : (m == 1) ? Wk : Wv;

#pragma unroll
    for (int it = 0; it < 4; ++it) {
        const int idx = tid + it * 256;
        const int r = idx >> 4, c4 = idx & 15;
        *reinterpret_cast<float4*>(&Xl[r][c4 * 4]) =
            *reinterpret_cast<const float4*>(in + (size_t)(n * L_ + l0 + r) * E_ + h * D_ + c4 * 4);
        *reinterpret_cast<float4*>(&Wl[r][c4 * 4]) =
            *reinterpret_cast<const float4*>(W + (size_t)r * D_ + c4 * 4);
    }
    __syncthreads();

    const int rp = tid & 31;
    const int eg = tid >> 5;
    float acc[2][8];
#pragma unroll
    for (int rr = 0; rr < 2; ++rr)
#pragma unroll
        for (int i = 0; i < 8; ++i) acc[rr][i] = 0.f;

#pragma unroll 4
    for (int d4 = 0; d4 < 16; ++d4) {
        const float4 xa = *reinterpret_cast<const float4*>(&Xl[rp][d4 * 4]);
        const float4 xb = *reinterpret_cast<const float4*>(&Xl[rp + 32][d4 * 4]);
#pragma unroll
        for (int i = 0; i < 8; ++i) {
            const float4 w = *reinterpret_cast<const float4*>(&Wl[eg * 8 + i][d4 * 4]);
            acc[0][i] += xa.x * w.x + xa.y * w.y + xa.z * w.z + xa.w * w.w;
            acc[1][i] += xb.x * w.x + xb.y * w.y + xb.z * w.z + xb.w * w.w;
        }
    }

    if (m == 0) {
#pragma unroll
        for (int rr = 0; rr < 2; ++rr)
#pragma unroll
            for (int i = 0; i < 8; ++i) acc[rr][i] *= QSCALE;
    }

    if (m < 2) {
        uint4 pa, pb;
        pa.x = cvtpk(acc[0][0], acc[0][1]); pa.y = cvtpk(acc[0][2], acc[0][3]);
        pa.z = cvtpk(acc[0][4], acc[0][5]); pa.w = cvtpk(acc[0][6], acc[0][7]);
        pb.x = cvtpk(acc[1][0], acc[1][1]); pb.y = cvtpk(acc[1][2], acc[1][3]);
        pb.z = cvtpk(acc[1][4], acc[1][5]); pb.w = cvtpk(acc[1][6], acc[1][7]);
        *reinterpret_cast<uint4*>(&Yl[rp][eg * 8]) = pa;
        *reinterpret_cast<uint4*>(&Yl[rp + 32][eg * 8]) = pb;
    } else {
#pragma unroll
        for (int i = 0; i < 8; ++i) {
            Yl[eg * 8 + i][rp] = f2bf(acc[0][i]);
            Yl[eg * 8 + i][rp + 32] = f2bf(acc[1][i]);
        }
    }
    __syncthreads();

    const int orow = tid >> 2;
    const int oc = (tid & 3) * 16;
    const uint4 v0 = *reinterpret_cast<const uint4*>(&Yl[orow][oc]);
    const uint4 v1 = *reinterpret_cast<const uint4*>(&Yl[orow][oc + 8]);
    unsigned short* dst;
    if (m == 0)      dst = Qp + ((size_t)nh * L_ + l0 + orow) * D_ + oc;
    else if (m == 1) dst = Kp + ((size_t)nh * L_ + l0 + orow) * D_ + oc;
    else             dst = Vt + ((size_t)nh * D_ + orow) * L_ + l0 + oc;
    *reinterpret_cast<uint4*>(dst) = v0;
    *reinterpret_cast<uint4*>(dst + 8) = v1;
}

// ---------------------------------------------------------------------------
// Kernel 2: bf16 MFMA flash attention, 32x32x16, in-register P, software
// pipelined, IN-BLOCK SPLIT-K.
// Block = 512 threads (8 waves). Waves 0-3: keys [0,1024); waves 4-7: keys
// [1024,2048). Each half has its own K(x2)/V(x3) staging set (80KB LDS total,
// 2 blocks/CU, 16 waves/CU = 4 waves/SIMD; grid 512 = fully resident).
// Per half, per iter t: [QK(t)] [PV(t-1) + ones-mfma lsum] [softmax(t)].
// End: barrier (makes ST[1] provably dead) -> half-1 waves write {ot,m,lsum}
// into ST[1]; barrier; half-0 waves merge (online-softmax algebra) + write AO.
// ---------------------------------------------------------------------------
__global__ __launch_bounds__(512, 4) void attn_kernel(
    const unsigned short* __restrict__ Qp, const unsigned short* __restrict__ Kp,
    const unsigned short* __restrict__ Vt, unsigned short* __restrict__ AO)
{
    // [half][buf]: bufs 0-1 = K double-buffer, 2-4 = V triple-buffer
    __shared__ __align__(16) unsigned short ST[2][5 * 4096];

    const int tid = threadIdx.x;
    const int phys = blockIdx.x;
    const int bid = (phys & 7) * 64 + (phys >> 3);   // bijective: 512 = 8*64
    const int qt = bid & 15;
    const int nh = bid >> 4;          // 4 heads per XCD -> K/V L2-resident
    const int n = nh >> 3, h = nh & 7;
    const int q0 = qt * 128;
    const int wave = tid >> 6;
    const int half = wave >> 2;       // key-range half
    const int w4 = wave & 3;          // wave-in-half: owns q rows w4*32..+31
    const int lane = tid & 63;
    const int l31 = lane & 31;
    const int hh  = lane >> 5;

    const unsigned short* __restrict__ Qb = Qp + (size_t)nh * (L_ * D_);
    const unsigned short* __restrict__ Kb = Kp + (size_t)nh * (L_ * D_);
    const unsigned short* __restrict__ Vb = Vt + (size_t)nh * (D_ * L_);

    unsigned short* const Kbuf0 = &ST[half][0];
    unsigned short* const Kbuf1 = &ST[half][4096];
    unsigned short* const Vbuf0 = &ST[half][2 * 4096];
    unsigned short* const Vbuf1 = &ST[half][3 * 4096];
    unsigned short* const Vbuf2 = &ST[half][4 * 4096];

    // staging geometry: granule G -> global (row=G>>3, c8=(G&7)^(row&7))
    const int G0 = w4 * 64 + lane;
    const int G1 = G0 + 256;
    const int r0 = G0 >> 3, c0 = (G0 & 7) ^ (r0 & 7);
    const int r1 = G1 >> 3, c1 = (G1 & 7) ^ (r1 & 7);

    const int kbase = half * 1024;    // first key of this half
    const unsigned short* ks0 = Kb + (size_t)(kbase + r0) * 64 + c0 * 8;
    const unsigned short* ks1 = Kb + (size_t)(kbase + r1) * 64 + c1 * 8;
    const unsigned short* vs0 = Vb + (size_t)r0 * L_ + kbase + c0 * 8;
    const unsigned short* vs1 = Vb + (size_t)r1 * L_ + kbase + c1 * 8;

    // prologue: stage kt=0
    gl_lds16(ks0, Kbuf0 + w4 * 512);
    gl_lds16(ks1, Kbuf0 + 2048 + w4 * 512);
    gl_lds16(vs0, Vbuf0 + w4 * 512);
    gl_lds16(vs1, Vbuf0 + 2048 + w4 * 512);

    // Q fragments straight to registers: B[k=d][col=q], q=q0+w4*32+l31
    const int qrow = q0 + w4 * 32 + l31;
    s16x8 qfrag[4];
#pragma unroll
    for (int ks = 0; ks < 4; ++ks)
        qfrag[ks] = *reinterpret_cast<const s16x8*>(
            Qb + (size_t)qrow * D_ + ks * 16 + hh * 8);

    // ones A-fragment for the lsum MFMA
    s16x8 onesf;
#pragma unroll
    for (int i = 0; i < 8; ++i) onesf[i] = (short)0x3F80;

    float m_ = -INFINITY;
    f32x16 lsacc = (f32x16)0.f;      // per-q key-sum accumulator
    f32x16 ot[2];
    ot[0] = (f32x16)0.f;
    ot[1] = (f32x16)0.f;
    s16x8 pf[4];                      // P frags of tile t-1, live across iters

    unsigned short* vprev = Vbuf2;
    unsigned short* vcur  = Vbuf0;
    unsigned short* vnext = Vbuf1;

    const int NT = (L_ / 2) / 64;     // 16 tiles per half

    for (int kt = 0; kt < NT; ++kt) {
        __syncthreads();   // stage(kt) landed everywhere; old buffers free
        if (kt + 1 < NT) {
            unsigned short* kn = ((kt + 1) & 1) ? Kbuf1 : Kbuf0;
            gl_lds16(ks0 + (kt + 1) * 4096, kn + w4 * 512);
            gl_lds16(ks1 + (kt + 1) * 4096, kn + 2048 + w4 * 512);
            gl_lds16(vs0 + (kt + 1) * 64,   vnext + w4 * 512);
            gl_lds16(vs1 + (kt + 1) * 64,   vnext + 2048 + w4 * 512);
        }
        const unsigned short* __restrict__ Kl = (kt & 1) ? Kbuf1 : Kbuf0;

        // ---- QK(t): S^T = K·Q^T (log2-domain scores) ----
        f32x16 st[2];
        __builtin_amdgcn_s_setprio(1);
#pragma unroll
        for (int kv = 0; kv < 2; ++kv) {
            st[kv] = (f32x16)0.f;
            const int krow = kv * 32 + l31;
#pragma unroll
            for (int ks = 0; ks < 4; ++ks) {
                const s16x8 kf = *reinterpret_cast<const s16x8*>(
                    &Kl[(krow * 64 + ks * 16 + hh * 8) ^ ((krow & 7) << 3)]);
                st[kv] = __builtin_amdgcn_mfma_f32_32x32x16_bf16(kf, qfrag[ks], st[kv], 0, 0, 0);
            }
        }

        // ---- PV(t-1) + ones-mfma lsum (in flight during softmax(t)) ----
        if (kt) {
#pragma unroll
            for (int dt = 0; dt < 2; ++dt) {
                const int drow = dt * 32 + l31;
#pragma unroll
                for (int kc = 0; kc < 4; ++kc) {
                    const s16x8 vf = *reinterpret_cast<const s16x8*>(
                        &vprev[(drow * 64 + kc * 16 + hh * 8) ^ ((drow & 7) << 3)]);
                    ot[dt] = __builtin_amdgcn_mfma_f32_32x32x16_bf16(vf, pf[kc], ot[dt], 0, 0, 0);
                }
            }
#pragma unroll
            for (int kc = 0; kc < 4; ++kc)
                lsacc = __builtin_amdgcn_mfma_f32_32x32x16_bf16(onesf, pf[kc], lsacc, 0, 0, 0);
        }
        __builtin_amdgcn_s_setprio(0);

        // ---- softmax(t): max3 tree + defer-max rescale + exp + pack ----
        const float t0 = max3f(st[0][0],  st[0][1],  st[0][2]);
        const float t1 = max3f(st[0][3],  st[0][4],  st[0][5]);
        const float t2 = max3f(st[0][6],  st[0][7],  st[0][8]);
        const float t3 = max3f(st[0][9],  st[0][10], st[0][11]);
        const float t4 = max3f(st[0][12], st[0][13], st[0][14]);
        const float t5 = max3f(st[0][15], st[1][0],  st[1][1]);
        const float t6 = max3f(st[1][2],  st[1][3],  st[1][4]);
        const float t7 = max3f(st[1][5],  st[1][6],  st[1][7]);
        const float t8 = max3f(st[1][8],  st[1][9],  st[1][10]);
        const float t9 = max3f(st[1][11], st[1][12], st[1][13]);
        const float ta = fmaxf(st[1][14], st[1][15]);
        const float u0 = max3f(t0, t1, t2);
        const float u1 = max3f(t3, t4, t5);
        const float u2 = max3f(t6, t7, t8);
        const float u3 = fmaxf(t9, ta);
        float tmax = fmaxf(max3f(u0, u1, u2), u3);
        tmax = fmaxf(tmax, __shfl_xor(tmax, 32));

        if (!__all(tmax <= m_ + 8.f)) {       // first tile: m_=-inf -> taken
            const float newm = fmaxf(m_, tmax);
            const float corr = exp2a(m_ - newm);   // 0 on first tile
            lsacc *= corr;
            ot[0] *= corr;
            ot[1] *= corr;
            m_ = newm;
        }

#pragma unroll
        for (int kv = 0; kv < 2; ++kv) {
            float p[16];
#pragma unroll
            for (int i = 0; i < 16; ++i) p[i] = exp2a(st[kv][i] - m_);  // <= 2^8
            unsigned int A0 = cvtpk(p[0],  p[1]),  B0 = cvtpk(p[2],  p[3]);
            unsigned int A1 = cvtpk(p[4],  p[5]),  B1 = cvtpk(p[6],  p[7]);
            unsigned int A2 = cvtpk(p[8],  p[9]),  B2 = cvtpk(p[10], p[11]);
            unsigned int A3 = cvtpk(p[12], p[13]), B3 = cvtpk(p[14], p[15]);
            swap32(A0, A1); swap32(B0, B1);
            swap32(A2, A3); swap32(B2, B3);
            u32x4 lo; lo[0] = A0; lo[1] = B0; lo[2] = A1; lo[3] = B1;
            u32x4 hi; hi[0] = A2; hi[1] = B2; hi[2] = A3; hi[3] = B3;
            pf[kv * 2 + 0] = __builtin_bit_cast(s16x8, lo);
            pf[kv * 2 + 1] = __builtin_bit_cast(s16x8, hi);
        }

        // rotate V ring
        unsigned short* tmp = vprev;
        vprev = vcur; vcur = vnext; vnext = tmp;
    }

    // ---- per-half pipeline epilogue: final PV + lsum ----
    __builtin_amdgcn_s_setprio(1);
#pragma unroll
    for (int dt = 0; dt < 2; ++dt) {
        const int drow = dt * 32 + l31;
#pragma unroll
        for (int kc = 0; kc < 4; ++kc) {
            const s16x8 vf = *reinterpret_cast<const s16x8*>(
                &vprev[(drow * 64 + kc * 16 + hh * 8) ^ ((drow & 7) << 3)]);
            ot[dt] = __builtin_amdgcn_mfma_f32_32x32x16_bf16(vf, pf[kc], ot[dt], 0, 0, 0);
        }
    }
#pragma unroll
    for (int kc = 0; kc < 4; ++kc)
        lsacc = __builtin_amdgcn_mfma_f32_32x32x16_bf16(onesf, pf[kc], lsacc, 0, 0, 0);
    __builtin_amdgcn_s_setprio(0);

    // ---- split-K merge via LDS ----
    // Barrier FIRST: all waves are past their last read of ST -> ST[1] is
    // provably dead before half-1 overwrites it (the round-7 NaN race).
    __syncthreads();
    float* mrg = reinterpret_cast<float*>(&ST[1][0]);
    const int slot = ((w4 << 6) + lane) * 36;      // 36 floats/lane, 16B-aligned
    if (half == 1) {
        *reinterpret_cast<f32x16*>(&mrg[slot])      = ot[0];
        *reinterpret_cast<f32x16*>(&mrg[slot + 16]) = ot[1];
        mrg[slot + 32] = m_;
        mrg[slot + 33] = lsacc[0];
    }
    __syncthreads();
    if (half == 0) {
        const f32x16 ob0 = *reinterpret_cast<const f32x16*>(&mrg[slot]);
        const f32x16 ob1 = *reinterpret_cast<const f32x16*>(&mrg[slot + 16]);
        const float mB = mrg[slot + 32];
        const float lB = mrg[slot + 33];
        const float mm = fmaxf(m_, mB);
        const float sA = exp2a(m_ - mm);
        const float sB = exp2a(mB - mm);
        const float inv = 1.f / (lsacc[0] * sA + lB * sB);
        ot[0] = ot[0] * sA + ob0 * sB;
        ot[1] = ot[1] * sA + ob1 * sB;

#pragma unroll
        for (int dt = 0; dt < 2; ++dt) {
#pragma unroll
            for (int r = 0; r < 4; ++r) {
                uint2 o;
                o.x = cvtpk(ot[dt][4 * r + 0] * inv, ot[dt][4 * r + 1] * inv);
                o.y = cvtpk(ot[dt][4 * r + 2] * inv, ot[dt][4 * r + 3] * inv);
                const size_t elem = ((size_t)n * L_ + qrow) * E_ + h * D_ + dt * 32 + r * 8 + hh * 4;
                *reinterpret_cast<uint2*>(AO + elem) = o;
            }
        }
    }
}

// ---------------------------------------------------------------------------
// Kernel 3: output projection via bf16 MFMA with Wo = Whi + Wlo split.
// ---------------------------------------------------------------------------
__global__ __launch_bounds__(256) void out_proj_kernel(
    const unsigned short* __restrict__ AO, const unsigned short* __restrict__ Whi,
    const unsigned short* __restrict__ Wlo, const float* __restrict__ bo,
    float* __restrict__ out)
{
    __shared__ __align__(16) unsigned short Adb[2][4096];
    __shared__ __align__(16) unsigned short Hdb[2][4096];
    __shared__ __align__(16) unsigned short Ldb[2][4096];

    const int tid = threadIdx.x;
    const int bid = blockIdx.x;
    const int mt = bid >> 3, nt = bid & 7;
    const int m0 = mt * 64, n0 = nt * 64;
    const int wave = tid >> 6, lane = tid & 63;
    const int ql = lane & 15, g = lane >> 4;

    const int G0 = wave * 64 + lane;
    const int G1 = G0 + 256;
    const int r0 = G0 >> 3, c0 = (G0 & 7) ^ (r0 & 7);
    const int r1 = G1 >> 3, c1 = (G1 & 7) ^ (r1 & 7);

    const unsigned short* as0 = AO + (size_t)(m0 + r0) * E_ + c0 * 8;
    const unsigned short* as1 = AO + (size_t)(m0 + r1) * E_ + c1 * 8;
    const unsigned short* hs0 = Whi + (size_t)(n0 + r0) * E_ + c0 * 8;
    const unsigned short* hs1 = Whi + (size_t)(n0 + r1) * E_ + c1 * 8;
    const unsigned short* ls0 = Wlo + (size_t)(n0 + r0) * E_ + c0 * 8;
    const unsigned short* ls1 = Wlo + (size_t)(n0 + r1) * E_ + c1 * 8;

    gl_lds16(as0, &Adb[0][wave * 512]);
    gl_lds16(as1, &Adb[0][2048 + wave * 512]);
    gl_lds16(hs0, &Hdb[0][wave * 512]);
    gl_lds16(hs1, &Hdb[0][2048 + wave * 512]);
    gl_lds16(ls0, &Ldb[0][wave * 512]);
    gl_lds16(ls1, &Ldb[0][2048 + wave * 512]);

    float bias[4];
#pragma unroll
    for (int t = 0; t < 4; ++t) bias[t] = bo[n0 + t * 16 + ql];

    f32x4 acc[4];
#pragma unroll
    for (int t = 0; t < 4; ++t) acc[t] = (f32x4){0.f, 0.f, 0.f, 0.f};

    const int arow = wave * 16 + ql;

    for (int kc = 0; kc < 8; ++kc) {
        const int b = kc & 1;
        __syncthreads();
        if (kc + 1 < 8) {
            const int nb = b ^ 1;
            const int ko = (kc + 1) * 64;
            gl_lds16(as0 + ko, &Adb[nb][wave * 512]);
            gl_lds16(as1 + ko, &Adb[nb][2048 + wave * 512]);
            gl_lds16(hs0 + ko, &Hdb[nb][wave * 512]);
            gl_lds16(hs1 + ko, &Hdb[nb][2048 + wave * 512]);
            gl_lds16(ls0 + ko, &Ldb[nb][wave * 512]);
            gl_lds16(ls1 + ko, &Ldb[nb][2048 + wave * 512]);
        }
        const unsigned short* __restrict__ Al = Adb[b];
        const unsigned short* __restrict__ Hl = Hdb[b];
        const unsigned short* __restrict__ Ll = Ldb[b];

        s16x8 af[2];
#pragma unroll
        for (int ks = 0; ks < 2; ++ks)
            af[ks] = *reinterpret_cast<const s16x8*>(
                &Al[(arow * 64 + ks * 32 + g * 8) ^ ((arow & 7) << 3)]);

        __builtin_amdgcn_s_setprio(1);
#pragma unroll
        for (int t = 0; t < 4; ++t) {
            const int wrow = t * 16 + ql;
#pragma unroll
            for (int ks = 0; ks < 2; ++ks) {
                const s16x8 bh = *reinterpret_cast<const s16x8*>(
                    &Hl[(wrow * 64 + ks * 32 + g * 8) ^ ((wrow & 7) << 3)]);
                acc[t] = __builtin_amdgcn_mfma_f32_16x16x32_bf16(af[ks], bh, acc[t], 0, 0, 0);
                const s16x8 bl = *reinterpret_cast<const s16x8*>(
                    &Ll[(wrow * 64 + ks * 32 + g * 8) ^ ((wrow & 7) << 3)]);
                acc[t] = __builtin_amdgcn_mfma_f32_16x16x32_bf16(af[ks], bl, acc[t], 0, 0, 0);
            }
        }
        __builtin_amdgcn_s_setprio(0);
    }

    // epilogue: D[m = m0+wave*16+g*4+r][n = n0+t*16+ql]
#pragma unroll
    for (int t = 0; t < 4; ++t) {
#pragma unroll
        for (int r = 0; r < 4; ++r) {
            out[(size_t)(m0 + wave * 16 + g * 4 + r) * E_ + n0 + t * 16 + ql] =
                acc[t][r] + bias[t];
        }
    }
}

// ---------------------------------------------------------------------------
extern "C" void kernel_launch(void* const* d_in, const int* in_sizes, int n_in,
                              void* d_out, int out_size, void* d_ws, size_t ws_size,
                              hipStream_t stream)
{
    const float* Q  = (const float*)d_in[0];
    const float* K  = (const float*)d_in[1];
    const float* V  = (const float*)d_in[2];
    const float* Wq = (const float*)d_in[3];
    const float* Wk = (const float*)d_in[4];
    const float* Wv = (const float*)d_in[5];
    const float* Wo = (const float*)d_in[6];
    const float* bo = (const float*)d_in[7];
    float* out = (float*)d_out;

    unsigned short* ws = (unsigned short*)d_ws;
    const size_t SZ = (size_t)N_ * H_ * L_ * D_;   // 4,194,304 elems
    unsigned short* Qp  = ws;
    unsigned short* Kp  = ws + SZ;
    unsigned short* Vt  = ws + 2 * SZ;
    unsigned short* AO  = ws + 3 * SZ;
    unsigned short* Whi = ws + 4 * SZ;
    unsigned short* Wlo = ws + 4 * SZ + 262144;

    qkv_proj_kernel<<<dim3(32, 32, 3), 256, 0, stream>>>(Q, K, V, Wq, Wk, Wv, Qp, Kp, Vt);
    wo_split_kernel<<<256, 256, 0, stream>>>(Wo, Whi, Wlo);
    attn_kernel<<<512, 512, 0, stream>>>(Qp, Kp, Vt, AO);
    out_proj_kernel<<<(8192 / 64) * (E_ / 64), 256, 0, stream>>>(AO, Whi, Wlo, bo, out);
}

// Round 9
// 116.906 us; speedup vs baseline: 1.2625x; 1.2625x over previous
//
#include <hip/hip_runtime.h>
#include <math.h>

#define N_ 4
#define L_ 2048
#define E_ 512
#define H_ 8
#define D_ 64

// SCALE = 1/sqrt(512) (reference scales by sqrt(embed_size));
// QSCALE = SCALE * log2(e): scores come out of QK^T in log2 domain.
#define QSCALE 0.06375871588055019f

typedef short s16x8 __attribute__((ext_vector_type(8)));
typedef float f32x4 __attribute__((ext_vector_type(4)));
typedef float f32x16 __attribute__((ext_vector_type(16)));
typedef unsigned int u32x4 __attribute__((ext_vector_type(4)));

typedef const __attribute__((address_space(1))) unsigned int ga_u32;
typedef __attribute__((address_space(3))) unsigned int lds_u32;

// async 16B global->LDS (dest = wave-uniform base + lane*16, linear)
__device__ __forceinline__ void gl_lds16(const unsigned short* g, unsigned short* l) {
    __builtin_amdgcn_global_load_lds((ga_u32*)g, (lds_u32*)l, 16, 0, 0);
}
__device__ __forceinline__ float exp2a(float x) {
    float r; asm("v_exp_f32 %0, %1" : "=v"(r) : "v"(x)); return r;
}
__device__ __forceinline__ unsigned int cvtpk(float lo, float hi) {
    unsigned int r; asm("v_cvt_pk_bf16_f32 %0, %1, %2" : "=v"(r) : "v"(lo), "v"(hi)); return r;
}
// v_permlane32_swap_b32 a, b: a<-{a_lo, b_lo}, b<-{a_hi, b_hi} (lane halves)
__device__ __forceinline__ void swap32(unsigned int& a, unsigned int& b) {
    asm volatile("v_permlane32_swap_b32 %0, %1" : "+v"(a), "+v"(b));
}
__device__ __forceinline__ float max3f(float a, float b, float c) {
    return fmaxf(fmaxf(a, b), c);   // clang fuses to v_max3_f32
}
__device__ __forceinline__ unsigned short f2bf(float x) {
    unsigned int u = __builtin_bit_cast(unsigned int, x);
    u = (u + 0x7FFFu + ((u >> 16) & 1u)) >> 16;   // RNE
    return (unsigned short)u;
}
__device__ __forceinline__ float bflo(unsigned int w) {
    return __builtin_bit_cast(float, w << 16);
}
__device__ __forceinline__ float bfhi(unsigned int w) {
    return __builtin_bit_cast(float, w & 0xFFFF0000u);
}

// ---------------------------------------------------------------------------
// Kernel 0: split Wo (fp32 512x512) into bf16 hi + bf16 residual lo.
// ---------------------------------------------------------------------------
__global__ __launch_bounds__(256) void wo_split_kernel(
    const float* __restrict__ Wo, unsigned short* __restrict__ Whi,
    unsigned short* __restrict__ Wlo)
{
    const int i = blockIdx.x * 256 + threadIdx.x;
    const float4 w = reinterpret_cast<const float4*>(Wo)[i];
    const unsigned int hxy = cvtpk(w.x, w.y);
    const unsigned int hzw = cvtpk(w.z, w.w);
    const unsigned int lxy = cvtpk(w.x - bflo(hxy), w.y - bfhi(hxy));
    const unsigned int lzw = cvtpk(w.z - bflo(hzw), w.w - bfhi(hzw));
    uint2 hh; hh.x = hxy; hh.y = hzw;
    uint2 ll; ll.x = lxy; ll.y = lzw;
    reinterpret_cast<uint2*>(Whi)[i] = hh;
    reinterpret_cast<uint2*>(Wlo)[i] = ll;
}

// ---------------------------------------------------------------------------
// Kernel 1: per-head QKV projection (fp32 compute, bf16 output).
// Q pre-scaled by QSCALE. Qp/Kp: [nh][l][d]; Vt: [nh][d][l].
// ---------------------------------------------------------------------------
__global__ __launch_bounds__(256) void qkv_proj_kernel(
    const float* __restrict__ Q, const float* __restrict__ K, const float* __restrict__ V,
    const float* __restrict__ Wq, const float* __restrict__ Wk, const float* __restrict__ Wv,
    unsigned short* __restrict__ Qp, unsigned short* __restrict__ Kp,
    unsigned short* __restrict__ Vt)
{
    __shared__ float Xl[64][68];
    __shared__ float Wl[64][68];
    __shared__ __align__(16) unsigned short Yl[64][72];

    const int tid = threadIdx.x;
    const int lt = blockIdx.x;
    const int nh = blockIdx.y;
    const int m  = blockIdx.z;       // 0:Q 1:K 2:V
    const int n = nh >> 3, h = nh & 7;
    const int l0 = lt * 64;

    const float* __restrict__ in = (m == 0) ? Q : (m == 1) ? K : V;
    const float* __restrict__ W  = (m == 0) ? Wq : (m == 1) ? Wk : Wv;

#pragma unroll
    for (int it = 0; it < 4; ++it) {
        const int idx = tid + it * 256;
        const int r = idx >> 4, c4 = idx & 15;
        *reinterpret_cast<float4*>(&Xl[r][c4 * 4]) =
            *reinterpret_cast<const float4*>(in + (size_t)(n * L_ + l0 + r) * E_ + h * D_ + c4 * 4);
        *reinterpret_cast<float4*>(&Wl[r][c4 * 4]) =
            *reinterpret_cast<const float4*>(W + (size_t)r * D_ + c4 * 4);
    }
    __syncthreads();

    const int rp = tid & 31;
    const int eg = tid >> 5;
    float acc[2][8];
#pragma unroll
    for (int rr = 0; rr < 2; ++rr)
#pragma unroll
        for (int i = 0; i < 8; ++i) acc[rr][i] = 0.f;

#pragma unroll 4
    for (int d4 = 0; d4 < 16; ++d4) {
        const float4 xa = *reinterpret_cast<const float4*>(&Xl[rp][d4 * 4]);
        const float4 xb = *reinterpret_cast<const float4*>(&Xl[rp + 32][d4 * 4]);
#pragma unroll
        for (int i = 0; i < 8; ++i) {
            const float4 w = *reinterpret_cast<const float4*>(&Wl[eg * 8 + i][d4 * 4]);
            acc[0][i] += xa.x * w.x + xa.y * w.y + xa.z * w.z + xa.w * w.w;
            acc[1][i] += xb.x * w.x + xb.y * w.y + xb.z * w.z + xb.w * w.w;
        }
    }

    if (m == 0) {
#pragma unroll
        for (int rr = 0; rr < 2; ++rr)
#pragma unroll
            for (int i = 0; i < 8; ++i) acc[rr][i] *= QSCALE;
    }

    if (m < 2) {
        uint4 pa, pb;
        pa.x = cvtpk(acc[0][0], acc[0][1]); pa.y = cvtpk(acc[0][2], acc[0][3]);
        pa.z = cvtpk(acc[0][4], acc[0][5]); pa.w = cvtpk(acc[0][6], acc[0][7]);
        pb.x = cvtpk(acc[1][0], acc[1][1]); pb.y = cvtpk(acc[1][2], acc[1][3]);
        pb.z = cvtpk(acc[1][4], acc[1][5]); pb.w = cvtpk(acc[1][6], acc[1][7]);
        *reinterpret_cast<uint4*>(&Yl[rp][eg * 8]) = pa;
        *reinterpret_cast<uint4*>(&Yl[rp + 32][eg * 8]) = pb;
    } else {
#pragma unroll
        for (int i = 0; i < 8; ++i) {
            Yl[eg * 8 + i][rp] = f2bf(acc[0][i]);
            Yl[eg * 8 + i][rp + 32] = f2bf(acc[1][i]);
        }
    }
    __syncthreads();

    const int orow = tid >> 2;
    const int oc = (tid & 3) * 16;
    const uint4 v0 = *reinterpret_cast<const uint4*>(&Yl[orow][oc]);
    const uint4 v1 = *reinterpret_cast<const uint4*>(&Yl[orow][oc + 8]);
    unsigned short* dst;
    if (m == 0)      dst = Qp + ((size_t)nh * L_ + l0 + orow) * D_ + oc;
    else if (m == 1) dst = Kp + ((size_t)nh * L_ + l0 + orow) * D_ + oc;
    else             dst = Vt + ((size_t)nh * D_ + orow) * L_ + l0 + oc;
    *reinterpret_cast<uint4*>(dst) = v0;
    *reinterpret_cast<uint4*>(dst + 8) = v1;
}

// ---------------------------------------------------------------------------
// Kernel 2: bf16 MFMA flash attention, 32x32x16, in-register P, software
// pipelined, IN-BLOCK SPLIT-K.  Register-dieted to fit 128 VGPR (4 waves/EU):
// the round-8 spill regression came from lsacc(16)+onesf(4) pushing demand
// past the __launch_bounds__(512,4) cap -> ones-MFMA lsum replaced by a VALU
// tree sum (overlapped by the already-issued PV(t-1) MFMAs); exp2 done
// in-place in st (no p[] temps).
// Block = 512 threads (8 waves). Waves 0-3: keys [0,1024); waves 4-7: keys
// [1024,2048). Each half has its own K(x2)/V(x3) staging set (80KB LDS,
// 2 blocks/CU, 16 waves/CU). Per half, per iter t:
// [QK(t)] [PV(t-1)] [softmax(t): max tree, rescale, exp2, sum tree, pack].
// End: barrier -> half-1 writes {ot,m,lsum} into ST[1] (dead) -> barrier ->
// half-0 merges (online-softmax algebra) and writes AO.
// ---------------------------------------------------------------------------
__global__ __launch_bounds__(512, 4) void attn_kernel(
    const unsigned short* __restrict__ Qp, const unsigned short* __restrict__ Kp,
    const unsigned short* __restrict__ Vt, unsigned short* __restrict__ AO)
{
    // [half][buf]: bufs 0-1 = K double-buffer, 2-4 = V triple-buffer
    __shared__ __align__(16) unsigned short ST[2][5 * 4096];

    const int tid = threadIdx.x;
    const int phys = blockIdx.x;
    const int bid = (phys & 7) * 64 + (phys >> 3);   // bijective: 512 = 8*64
    const int qt = bid & 15;
    const int nh = bid >> 4;          // 4 heads per XCD -> K/V L2-resident
    const int n = nh >> 3, h = nh & 7;
    const int q0 = qt * 128;
    const int wave = tid >> 6;
    const int half = wave >> 2;       // key-range half
    const int w4 = wave & 3;          // wave-in-half: owns q rows w4*32..+31
    const int lane = tid & 63;
    const int l31 = lane & 31;
    const int hh  = lane >> 5;

    const unsigned short* __restrict__ Qb = Qp + (size_t)nh * (L_ * D_);
    const unsigned short* __restrict__ Kb = Kp + (size_t)nh * (L_ * D_);
    const unsigned short* __restrict__ Vb = Vt + (size_t)nh * (D_ * L_);

    unsigned short* const Kbuf0 = &ST[half][0];
    unsigned short* const Kbuf1 = &ST[half][4096];
    unsigned short* const Vbuf0 = &ST[half][2 * 4096];
    unsigned short* const Vbuf1 = &ST[half][3 * 4096];
    unsigned short* const Vbuf2 = &ST[half][4 * 4096];

    // staging geometry: granule G -> global (row=G>>3, c8=(G&7)^(row&7))
    const int G0 = w4 * 64 + lane;
    const int G1 = G0 + 256;
    const int r0 = G0 >> 3, c0 = (G0 & 7) ^ (r0 & 7);
    const int r1 = G1 >> 3, c1 = (G1 & 7) ^ (r1 & 7);

    const int kbase = half * 1024;    // first key of this half
    const unsigned short* ks0 = Kb + (size_t)(kbase + r0) * 64 + c0 * 8;
    const unsigned short* ks1 = Kb + (size_t)(kbase + r1) * 64 + c1 * 8;
    const unsigned short* vs0 = Vb + (size_t)r0 * L_ + kbase + c0 * 8;
    const unsigned short* vs1 = Vb + (size_t)r1 * L_ + kbase + c1 * 8;

    // prologue: stage kt=0
    gl_lds16(ks0, Kbuf0 + w4 * 512);
    gl_lds16(ks1, Kbuf0 + 2048 + w4 * 512);
    gl_lds16(vs0, Vbuf0 + w4 * 512);
    gl_lds16(vs1, Vbuf0 + 2048 + w4 * 512);

    // Q fragments straight to registers: B[k=d][col=q], q=q0+w4*32+l31
    const int qrow = q0 + w4 * 32 + l31;
    s16x8 qfrag[4];
#pragma unroll
    for (int ks = 0; ks < 4; ++ks)
        qfrag[ks] = *reinterpret_cast<const s16x8*>(
            Qb + (size_t)qrow * D_ + ks * 16 + hh * 8);

    float m_ = -INFINITY;
    float lsum = 0.f;
    f32x16 ot[2];
    ot[0] = (f32x16)0.f;
    ot[1] = (f32x16)0.f;
    s16x8 pf[4];                      // P frags of tile t-1, live across iters

    unsigned short* vprev = Vbuf2;
    unsigned short* vcur  = Vbuf0;
    unsigned short* vnext = Vbuf1;

    const int NT = (L_ / 2) / 64;     // 16 tiles per half

    for (int kt = 0; kt < NT; ++kt) {
        __syncthreads();   // stage(kt) landed everywhere; old buffers free
        if (kt + 1 < NT) {
            unsigned short* kn = ((kt + 1) & 1) ? Kbuf1 : Kbuf0;
            gl_lds16(ks0 + (kt + 1) * 4096, kn + w4 * 512);
            gl_lds16(ks1 + (kt + 1) * 4096, kn + 2048 + w4 * 512);
            gl_lds16(vs0 + (kt + 1) * 64,   vnext + w4 * 512);
            gl_lds16(vs1 + (kt + 1) * 64,   vnext + 2048 + w4 * 512);
        }
        const unsigned short* __restrict__ Kl = (kt & 1) ? Kbuf1 : Kbuf0;

        // ---- QK(t): S^T = K·Q^T (log2-domain scores) ----
        f32x16 st[2];
        __builtin_amdgcn_s_setprio(1);
#pragma unroll
        for (int kv = 0; kv < 2; ++kv) {
            st[kv] = (f32x16)0.f;
            const int krow = kv * 32 + l31;
#pragma unroll
            for (int ks = 0; ks < 4; ++ks) {
                const s16x8 kf = *reinterpret_cast<const s16x8*>(
                    &Kl[(krow * 64 + ks * 16 + hh * 8) ^ ((krow & 7) << 3)]);
                st[kv] = __builtin_amdgcn_mfma_f32_32x32x16_bf16(kf, qfrag[ks], st[kv], 0, 0, 0);
            }
        }

        // ---- PV(t-1) (in flight during softmax(t)) ----
        if (kt) {
#pragma unroll
            for (int dt = 0; dt < 2; ++dt) {
                const int drow = dt * 32 + l31;
#pragma unroll
                for (int kc = 0; kc < 4; ++kc) {
                    const s16x8 vf = *reinterpret_cast<const s16x8*>(
                        &vprev[(drow * 64 + kc * 16 + hh * 8) ^ ((drow & 7) << 3)]);
                    ot[dt] = __builtin_amdgcn_mfma_f32_32x32x16_bf16(vf, pf[kc], ot[dt], 0, 0, 0);
                }
            }
        }
        __builtin_amdgcn_s_setprio(0);

        // ---- softmax(t): max3 tree + defer-max rescale + exp + sum + pack ----
        const float t0 = max3f(st[0][0],  st[0][1],  st[0][2]);
        const float t1 = max3f(st[0][3],  st[0][4],  st[0][5]);
        const float t2 = max3f(st[0][6],  st[0][7],  st[0][8]);
        const float t3 = max3f(st[0][9],  st[0][10], st[0][11]);
        const float t4 = max3f(st[0][12], st[0][13], st[0][14]);
        const float t5 = max3f(st[0][15], st[1][0],  st[1][1]);
        const float t6 = max3f(st[1][2],  st[1][3],  st[1][4]);
        const float t7 = max3f(st[1][5],  st[1][6],  st[1][7]);
        const float t8 = max3f(st[1][8],  st[1][9],  st[1][10]);
        const float t9 = max3f(st[1][11], st[1][12], st[1][13]);
        const float ta = fmaxf(st[1][14], st[1][15]);
        const float u0 = max3f(t0, t1, t2);
        const float u1 = max3f(t3, t4, t5);
        const float u2 = max3f(t6, t7, t8);
        const float u3 = fmaxf(t9, ta);
        float tmax = fmaxf(max3f(u0, u1, u2), u3);
        tmax = fmaxf(tmax, __shfl_xor(tmax, 32));

        if (!__all(tmax <= m_ + 8.f)) {       // first tile: m_=-inf -> taken
            const float newm = fmaxf(m_, tmax);
            const float corr = exp2a(m_ - newm);   // 0 on first tile
            lsum *= corr;
            ot[0] *= corr;
            ot[1] *= corr;
            m_ = newm;
        }

        // exp2 in place (<= 2^8 bound via defer-max)
#pragma unroll
        for (int kv = 0; kv < 2; ++kv)
#pragma unroll
            for (int i = 0; i < 16; ++i) st[kv][i] = exp2a(st[kv][i] - m_);

        // tree sum of 32 values (4 partials; overlapped by PV MFMAs above)
        {
            float s0 = 0.f, s1 = 0.f, s2 = 0.f, s3 = 0.f;
#pragma unroll
            for (int i = 0; i < 4; ++i) {
                s0 += st[0][i];      s1 += st[0][i + 4];
                s2 += st[0][i + 8];  s3 += st[0][i + 12];
                s0 += st[1][i];      s1 += st[1][i + 4];
                s2 += st[1][i + 8];  s3 += st[1][i + 12];
            }
            float ts = (s0 + s1) + (s2 + s3);
            ts += __shfl_xor(ts, 32);
            lsum += ts;
        }

        // pack P -> PV B-frags (cvt_pk + permlane32_swap)
#pragma unroll
        for (int kv = 0; kv < 2; ++kv) {
            unsigned int A0 = cvtpk(st[kv][0],  st[kv][1]),  B0 = cvtpk(st[kv][2],  st[kv][3]);
            unsigned int A1 = cvtpk(st[kv][4],  st[kv][5]),  B1 = cvtpk(st[kv][6],  st[kv][7]);
            unsigned int A2 = cvtpk(st[kv][8],  st[kv][9]),  B2 = cvtpk(st[kv][10], st[kv][11]);
            unsigned int A3 = cvtpk(st[kv][12], st[kv][13]), B3 = cvtpk(st[kv][14], st[kv][15]);
            swap32(A0, A1); swap32(B0, B1);
            swap32(A2, A3); swap32(B2, B3);
            u32x4 lo; lo[0] = A0; lo[1] = B0; lo[2] = A1; lo[3] = B1;
            u32x4 hi; hi[0] = A2; hi[1] = B2; hi[2] = A3; hi[3] = B3;
            pf[kv * 2 + 0] = __builtin_bit_cast(s16x8, lo);
            pf[kv * 2 + 1] = __builtin_bit_cast(s16x8, hi);
        }

        // rotate V ring
        unsigned short* tmp = vprev;
        vprev = vcur; vcur = vnext; vnext = tmp;
    }

    // ---- per-half pipeline epilogue: final PV ----
    __builtin_amdgcn_s_setprio(1);
#pragma unroll
    for (int dt = 0; dt < 2; ++dt) {
        const int drow = dt * 32 + l31;
#pragma unroll
        for (int kc = 0; kc < 4; ++kc) {
            const s16x8 vf = *reinterpret_cast<const s16x8*>(
                &vprev[(drow * 64 + kc * 16 + hh * 8) ^ ((drow & 7) << 3)]);
            ot[dt] = __builtin_amdgcn_mfma_f32_32x32x16_bf16(vf, pf[kc], ot[dt], 0, 0, 0);
        }
    }
    __builtin_amdgcn_s_setprio(0);

    // ---- split-K merge via LDS ----
    // Barrier FIRST: all waves past their last read of ST -> ST[1] provably
    // dead before half-1 overwrites it (the round-7 NaN race fix).
    __syncthreads();
    float* mrg = reinterpret_cast<float*>(&ST[1][0]);
    const int slot = ((w4 << 6) + lane) * 36;      // 36 floats/lane, 16B-aligned
    if (half == 1) {
        *reinterpret_cast<f32x16*>(&mrg[slot])      = ot[0];
        *reinterpret_cast<f32x16*>(&mrg[slot + 16]) = ot[1];
        mrg[slot + 32] = m_;
        mrg[slot + 33] = lsum;
    }
    __syncthreads();
    if (half == 0) {
        const f32x16 ob0 = *reinterpret_cast<const f32x16*>(&mrg[slot]);
        const f32x16 ob1 = *reinterpret_cast<const f32x16*>(&mrg[slot + 16]);
        const float mB = mrg[slot + 32];
        const float lB = mrg[slot + 33];
        const float mm = fmaxf(m_, mB);
        const float sA = exp2a(m_ - mm);
        const float sB = exp2a(mB - mm);
        const float inv = 1.f / (lsum * sA + lB * sB);
        ot[0] = ot[0] * sA + ob0 * sB;
        ot[1] = ot[1] * sA + ob1 * sB;

#pragma unroll
        for (int dt = 0; dt < 2; ++dt) {
#pragma unroll
            for (int r = 0; r < 4; ++r) {
                uint2 o;
                o.x = cvtpk(ot[dt][4 * r + 0] * inv, ot[dt][4 * r + 1] * inv);
                o.y = cvtpk(ot[dt][4 * r + 2] * inv, ot[dt][4 * r + 3] * inv);
                const size_t elem = ((size_t)n * L_ + qrow) * E_ + h * D_ + dt * 32 + r * 8 + hh * 4;
                *reinterpret_cast<uint2*>(AO + elem) = o;
            }
        }
    }
}

// ---------------------------------------------------------------------------
// Kernel 3: output projection via bf16 MFMA with Wo = Whi + Wlo split.
// ---------------------------------------------------------------------------
__global__ __launch_bounds__(256) void out_proj_kernel(
    const unsigned short* __restrict__ AO, const unsigned short* __restrict__ Whi,
    const unsigned short* __restrict__ Wlo, const float* __restrict__ bo,
    float* __restrict__ out)
{
    __shared__ __align__(16) unsigned short Adb[2][4096];
    __shared__ __align__(16) unsigned short Hdb[2][4096];
    __shared__ __align__(16) unsigned short Ldb[2][4096];

    const int tid = threadIdx.x;
    const int bid = blockIdx.x;
    const int mt = bid >> 3, nt = bid & 7;
    const int m0 = mt * 64, n0 = nt * 64;
    const int wave = tid >> 6, lane = tid & 63;
    const int ql = lane & 15, g = lane >> 4;

    const int G0 = wave * 64 + lane;
    const int G1 = G0 + 256;
    const int r0 = G0 >> 3, c0 = (G0 & 7) ^ (r0 & 7);
    const int r1 = G1 >> 3, c1 = (G1 & 7) ^ (r1 & 7);

    const unsigned short* as0 = AO + (size_t)(m0 + r0) * E_ + c0 * 8;
    const unsigned short* as1 = AO + (size_t)(m0 + r1) * E_ + c1 * 8;
    const unsigned short* hs0 = Whi + (size_t)(n0 + r0) * E_ + c0 * 8;
    const unsigned short* hs1 = Whi + (size_t)(n0 + r1) * E_ + c1 * 8;
    const unsigned short* ls0 = Wlo + (size_t)(n0 + r0) * E_ + c0 * 8;
    const unsigned short* ls1 = Wlo + (size_t)(n0 + r1) * E_ + c1 * 8;

    gl_lds16(as0, &Adb[0][wave * 512]);
    gl_lds16(as1, &Adb[0][2048 + wave * 512]);
    gl_lds16(hs0, &Hdb[0][wave * 512]);
    gl_lds16(hs1, &Hdb[0][2048 + wave * 512]);
    gl_lds16(ls0, &Ldb[0][wave * 512]);
    gl_lds16(ls1, &Ldb[0][2048 + wave * 512]);

    float bias[4];
#pragma unroll
    for (int t = 0; t < 4; ++t) bias[t] = bo[n0 + t * 16 + ql];

    f32x4 acc[4];
#pragma unroll
    for (int t = 0; t < 4; ++t) acc[t] = (f32x4){0.f, 0.f, 0.f, 0.f};

    const int arow = wave * 16 + ql;

    for (int kc = 0; kc < 8; ++kc) {
        const int b = kc & 1;
        __syncthreads();
        if (kc + 1 < 8) {
            const int nb = b ^ 1;
            const int ko = (kc + 1) * 64;
            gl_lds16(as0 + ko, &Adb[nb][wave * 512]);
            gl_lds16(as1 + ko, &Adb[nb][2048 + wave * 512]);
            gl_lds16(hs0 + ko, &Hdb[nb][wave * 512]);
            gl_lds16(hs1 + ko, &Hdb[nb][2048 + wave * 512]);
            gl_lds16(ls0 + ko, &Ldb[nb][wave * 512]);
            gl_lds16(ls1 + ko, &Ldb[nb][2048 + wave * 512]);
        }
        const unsigned short* __restrict__ Al = Adb[b];
        const unsigned short* __restrict__ Hl = Hdb[b];
        const unsigned short* __restrict__ Ll = Ldb[b];

        s16x8 af[2];
#pragma unroll
        for (int ks = 0; ks < 2; ++ks)
            af[ks] = *reinterpret_cast<const s16x8*>(
                &Al[(arow * 64 + ks * 32 + g * 8) ^ ((arow & 7) << 3)]);

        __builtin_amdgcn_s_setprio(1);
#pragma unroll
        for (int t = 0; t < 4; ++t) {
            const int wrow = t * 16 + ql;
#pragma unroll
            for (int ks = 0; ks < 2; ++ks) {
                const s16x8 bh = *reinterpret_cast<const s16x8*>(
                    &Hl[(wrow * 64 + ks * 32 + g * 8) ^ ((wrow & 7) << 3)]);
                acc[t] = __builtin_amdgcn_mfma_f32_16x16x32_bf16(af[ks], bh, acc[t], 0, 0, 0);
                const s16x8 bl = *reinterpret_cast<const s16x8*>(
                    &Ll[(wrow * 64 + ks * 32 + g * 8) ^ ((wrow & 7) << 3)]);
                acc[t] = __builtin_amdgcn_mfma_f32_16x16x32_bf16(af[ks], bl, acc[t], 0, 0, 0);
            }
        }
        __builtin_amdgcn_s_setprio(0);
    }

    // epilogue: D[m = m0+wave*16+g*4+r][n = n0+t*16+ql]
#pragma unroll
    for (int t = 0; t < 4; ++t) {
#pragma unroll
        for (int r = 0; r < 4; ++r) {
            out[(size_t)(m0 + wave * 16 + g * 4 + r) * E_ + n0 + t * 16 + ql] =
                acc[t][r] + bias[t];
        }
    }
}

// ---------------------------------------------------------------------------
extern "C" void kernel_launch(void* const* d_in, const int* in_sizes, int n_in,
                              void* d_out, int out_size, void* d_ws, size_t ws_size,
                              hipStream_t stream)
{
    const float* Q  = (const float*)d_in[0];
    const float* K  = (const float*)d_in[1];
    const float* V  = (const float*)d_in[2];
    const float* Wq = (const float*)d_in[3];
    const float* Wk = (const float*)d_in[4];
    const float* Wv = (const float*)d_in[5];
    const float* Wo = (const float*)d_in[6];
    const float* bo = (const float*)d_in[7];
    float* out = (float*)d_out;

    unsigned short* ws = (unsigned short*)d_ws;
    const size_t SZ = (size_t)N_ * H_ * L_ * D_;   // 4,194,304 elems
    unsigned short* Qp  = ws;
    unsigned short* Kp  = ws + SZ;
    unsigned short* Vt  = ws + 2 * SZ;
    unsigned short* AO  = ws + 3 * SZ;
    unsigned short* Whi = ws + 4 * SZ;
    unsigned short* Wlo = ws + 4 * SZ + 262144;

    qkv_proj_kernel<<<dim3(32, 32, 3), 256, 0, stream>>>(Q, K, V, Wq, Wk, Wv, Qp, Kp, Vt);
    wo_split_kernel<<<256, 256, 0, stream>>>(Wo, Whi, Wlo);
    attn_kernel<<<512, 512, 0, stream>>>(Qp, Kp, Vt, AO);
    out_proj_kernel<<<(8192 / 64) * (E_ / 64), 256, 0, stream>>>(AO, Whi, Wlo, bo, out);
}

// Round 10
// 114.178 us; speedup vs baseline: 1.2926x; 1.0239x over previous
//
#include <hip/hip_runtime.h>
#include <math.h>

#define N_ 4
#define L_ 2048
#define E_ 512
#define H_ 8
#define D_ 64

// SCALE = 1/sqrt(512) (reference scales by sqrt(embed_size));
// QSCALE = SCALE * log2(e): scores come out of QK^T in log2 domain.
#define QSCALE 0.06375871588055019f

typedef short s16x8 __attribute__((ext_vector_type(8)));
typedef float f32x4 __attribute__((ext_vector_type(4)));
typedef float f32x16 __attribute__((ext_vector_type(16)));
typedef unsigned int u32x4 __attribute__((ext_vector_type(4)));

typedef const __attribute__((address_space(1))) unsigned int ga_u32;
typedef __attribute__((address_space(3))) unsigned int lds_u32;

// async 16B global->LDS (dest = wave-uniform base + lane*16, linear)
__device__ __forceinline__ void gl_lds16(const unsigned short* g, unsigned short* l) {
    __builtin_amdgcn_global_load_lds((ga_u32*)g, (lds_u32*)l, 16, 0, 0);
}
__device__ __forceinline__ float exp2a(float x) {
    float r; asm("v_exp_f32 %0, %1" : "=v"(r) : "v"(x)); return r;
}
__device__ __forceinline__ unsigned int cvtpk(float lo, float hi) {
    unsigned int r; asm("v_cvt_pk_bf16_f32 %0, %1, %2" : "=v"(r) : "v"(lo), "v"(hi)); return r;
}
// v_permlane32_swap_b32 a, b: a<-{a_lo, b_lo}, b<-{a_hi, b_hi} (lane halves)
__device__ __forceinline__ void swap32(unsigned int& a, unsigned int& b) {
    asm volatile("v_permlane32_swap_b32 %0, %1" : "+v"(a), "+v"(b));
}
__device__ __forceinline__ float max3f(float a, float b, float c) {
    return fmaxf(fmaxf(a, b), c);   // clang fuses to v_max3_f32
}
__device__ __forceinline__ unsigned short f2bf(float x) {
    unsigned int u = __builtin_bit_cast(unsigned int, x);
    u = (u + 0x7FFFu + ((u >> 16) & 1u)) >> 16;   // RNE
    return (unsigned short)u;
}
__device__ __forceinline__ float bflo(unsigned int w) {
    return __builtin_bit_cast(float, w << 16);
}
__device__ __forceinline__ float bfhi(unsigned int w) {
    return __builtin_bit_cast(float, w & 0xFFFF0000u);
}

// ---------------------------------------------------------------------------
// Kernel 0: split Wo (fp32 512x512) into bf16 hi + bf16 residual lo.
// ---------------------------------------------------------------------------
__global__ __launch_bounds__(256) void wo_split_kernel(
    const float* __restrict__ Wo, unsigned short* __restrict__ Whi,
    unsigned short* __restrict__ Wlo)
{
    const int i = blockIdx.x * 256 + threadIdx.x;
    const float4 w = reinterpret_cast<const float4*>(Wo)[i];
    const unsigned int hxy = cvtpk(w.x, w.y);
    const unsigned int hzw = cvtpk(w.z, w.w);
    const unsigned int lxy = cvtpk(w.x - bflo(hxy), w.y - bfhi(hxy));
    const unsigned int lzw = cvtpk(w.z - bflo(hzw), w.w - bfhi(hzw));
    uint2 hh; hh.x = hxy; hh.y = hzw;
    uint2 ll; ll.x = lxy; ll.y = lzw;
    reinterpret_cast<uint2*>(Whi)[i] = hh;
    reinterpret_cast<uint2*>(Wlo)[i] = ll;
}

// ---------------------------------------------------------------------------
// Kernel 1: per-head QKV projection (fp32 compute, bf16 output).
// Q pre-scaled by QSCALE. Qp/Kp: [nh][l][d]; Vt: [nh][d][l].
// ---------------------------------------------------------------------------
__global__ __launch_bounds__(256) void qkv_proj_kernel(
    const float* __restrict__ Q, const float* __restrict__ K, const float* __restrict__ V,
    const float* __restrict__ Wq, const float* __restrict__ Wk, const float* __restrict__ Wv,
    unsigned short* __restrict__ Qp, unsigned short* __restrict__ Kp,
    unsigned short* __restrict__ Vt)
{
    __shared__ float Xl[64][68];
    __shared__ float Wl[64][68];
    __shared__ __align__(16) unsigned short Yl[64][72];

    const int tid = threadIdx.x;
    const int lt = blockIdx.x;
    const int nh = blockIdx.y;
    const int m  = blockIdx.z;       // 0:Q 1:K 2:V
    const int n = nh >> 3, h = nh & 7;
    const int l0 = lt * 64;

    const float* __restrict__ in = (m == 0) ? Q : (m == 1) ? K : V;
    const float* __restrict__ W  = (m == 0) ? Wq : (m == 1) ? Wk : Wv;

#pragma unroll
    for (int it = 0; it < 4; ++it) {
        const int idx = tid + it * 256;
        const int r = idx >> 4, c4 = idx & 15;
        *reinterpret_cast<float4*>(&Xl[r][c4 * 4]) =
            *reinterpret_cast<const float4*>(in + (size_t)(n * L_ + l0 + r) * E_ + h * D_ + c4 * 4);
        *reinterpret_cast<float4*>(&Wl[r][c4 * 4]) =
            *reinterpret_cast<const float4*>(W + (size_t)r * D_ + c4 * 4);
    }
    __syncthreads();

    const int rp = tid & 31;
    const int eg = tid >> 5;
    float acc[2][8];
#pragma unroll
    for (int rr = 0; rr < 2; ++rr)
#pragma unroll
        for (int i = 0; i < 8; ++i) acc[rr][i] = 0.f;

#pragma unroll 4
    for (int d4 = 0; d4 < 16; ++d4) {
        const float4 xa = *reinterpret_cast<const float4*>(&Xl[rp][d4 * 4]);
        const float4 xb = *reinterpret_cast<const float4*>(&Xl[rp + 32][d4 * 4]);
#pragma unroll
        for (int i = 0; i < 8; ++i) {
            const float4 w = *reinterpret_cast<const float4*>(&Wl[eg * 8 + i][d4 * 4]);
            acc[0][i] += xa.x * w.x + xa.y * w.y + xa.z * w.z + xa.w * w.w;
            acc[1][i] += xb.x * w.x + xb.y * w.y + xb.z * w.z + xb.w * w.w;
        }
    }

    if (m == 0) {
#pragma unroll
        for (int rr = 0; rr < 2; ++rr)
#pragma unroll
            for (int i = 0; i < 8; ++i) acc[rr][i] *= QSCALE;
    }

    if (m < 2) {
        uint4 pa, pb;
        pa.x = cvtpk(acc[0][0], acc[0][1]); pa.y = cvtpk(acc[0][2], acc[0][3]);
        pa.z = cvtpk(acc[0][4], acc[0][5]); pa.w = cvtpk(acc[0][6], acc[0][7]);
        pb.x = cvtpk(acc[1][0], acc[1][1]); pb.y = cvtpk(acc[1][2], acc[1][3]);
        pb.z = cvtpk(acc[1][4], acc[1][5]); pb.w = cvtpk(acc[1][6], acc[1][7]);
        *reinterpret_cast<uint4*>(&Yl[rp][eg * 8]) = pa;
        *reinterpret_cast<uint4*>(&Yl[rp + 32][eg * 8]) = pb;
    } else {
#pragma unroll
        for (int i = 0; i < 8; ++i) {
            Yl[eg * 8 + i][rp] = f2bf(acc[0][i]);
            Yl[eg * 8 + i][rp + 32] = f2bf(acc[1][i]);
        }
    }
    __syncthreads();

    const int orow = tid >> 2;
    const int oc = (tid & 3) * 16;
    const uint4 v0 = *reinterpret_cast<const uint4*>(&Yl[orow][oc]);
    const uint4 v1 = *reinterpret_cast<const uint4*>(&Yl[orow][oc + 8]);
    unsigned short* dst;
    if (m == 0)      dst = Qp + ((size_t)nh * L_ + l0 + orow) * D_ + oc;
    else if (m == 1) dst = Kp + ((size_t)nh * L_ + l0 + orow) * D_ + oc;
    else             dst = Vt + ((size_t)nh * D_ + orow) * L_ + l0 + oc;
    *reinterpret_cast<uint4*>(dst) = v0;
    *reinterpret_cast<uint4*>(dst + 8) = v1;
}

// ---------------------------------------------------------------------------
// Kernel 2: bf16 MFMA flash attention, 32x32x16, in-register P, software
// pipelined, IN-BLOCK SPLIT-K.
// __launch_bounds__(512, 2): the 2nd arg is min BLOCKS/CU (CUDA semantics) --
// rounds 8/9 used (512,4) = 32 waves/CU = 64-VGPR cap -> persistent scratch
// spills (VGPR_Count=64, +5..26MB FETCH). (512,2) = 16 waves/CU = 128-VGPR
// cap >= ~121 demand -> no spill; LDS (80KB) enforces 2 blocks/CU anyway.
// Block = 512 threads (8 waves). Waves 0-3: keys [0,1024); waves 4-7: keys
// [1024,2048). Each half: own K(x2)/V(x3) staging. Per half, per iter t:
// [QK(t)] [PV(t-1)] [softmax(t)]. End: barrier -> half-1 writes {ot,m,lsum}
// into ST[1] (dead) -> barrier -> half-0 merges and writes AO.
// ---------------------------------------------------------------------------
__global__ __launch_bounds__(512, 2) void attn_kernel(
    const unsigned short* __restrict__ Qp, const unsigned short* __restrict__ Kp,
    const unsigned short* __restrict__ Vt, unsigned short* __restrict__ AO)
{
    // [half][buf]: bufs 0-1 = K double-buffer, 2-4 = V triple-buffer
    __shared__ __align__(16) unsigned short ST[2][5 * 4096];

    const int tid = threadIdx.x;
    const int phys = blockIdx.x;
    const int bid = (phys & 7) * 64 + (phys >> 3);   // bijective: 512 = 8*64
    const int qt = bid & 15;
    const int nh = bid >> 4;          // 4 heads per XCD -> K/V L2-resident
    const int n = nh >> 3, h = nh & 7;
    const int q0 = qt * 128;
    const int wave = tid >> 6;
    const int half = wave >> 2;       // key-range half
    const int w4 = wave & 3;          // wave-in-half: owns q rows w4*32..+31
    const int lane = tid & 63;
    const int l31 = lane & 31;
    const int hh  = lane >> 5;

    const unsigned short* __restrict__ Qb = Qp + (size_t)nh * (L_ * D_);
    const unsigned short* __restrict__ Kb = Kp + (size_t)nh * (L_ * D_);
    const unsigned short* __restrict__ Vb = Vt + (size_t)nh * (D_ * L_);

    unsigned short* const Kbuf0 = &ST[half][0];
    unsigned short* const Kbuf1 = &ST[half][4096];
    unsigned short* const Vbuf0 = &ST[half][2 * 4096];
    unsigned short* const Vbuf1 = &ST[half][3 * 4096];
    unsigned short* const Vbuf2 = &ST[half][4 * 4096];

    // staging geometry: granule G -> global (row=G>>3, c8=(G&7)^(row&7))
    const int G0 = w4 * 64 + lane;
    const int G1 = G0 + 256;
    const int r0 = G0 >> 3, c0 = (G0 & 7) ^ (r0 & 7);
    const int r1 = G1 >> 3, c1 = (G1 & 7) ^ (r1 & 7);

    const int kbase = half * 1024;    // first key of this half
    const unsigned short* ks0 = Kb + (size_t)(kbase + r0) * 64 + c0 * 8;
    const unsigned short* ks1 = Kb + (size_t)(kbase + r1) * 64 + c1 * 8;
    const unsigned short* vs0 = Vb + (size_t)r0 * L_ + kbase + c0 * 8;
    const unsigned short* vs1 = Vb + (size_t)r1 * L_ + kbase + c1 * 8;

    // prologue: stage kt=0
    gl_lds16(ks0, Kbuf0 + w4 * 512);
    gl_lds16(ks1, Kbuf0 + 2048 + w4 * 512);
    gl_lds16(vs0, Vbuf0 + w4 * 512);
    gl_lds16(vs1, Vbuf0 + 2048 + w4 * 512);

    // Q fragments straight to registers: B[k=d][col=q], q=q0+w4*32+l31
    const int qrow = q0 + w4 * 32 + l31;
    s16x8 qfrag[4];
#pragma unroll
    for (int ks = 0; ks < 4; ++ks)
        qfrag[ks] = *reinterpret_cast<const s16x8*>(
            Qb + (size_t)qrow * D_ + ks * 16 + hh * 8);

    float m_ = -INFINITY;
    float lsum = 0.f;
    f32x16 ot[2];
    ot[0] = (f32x16)0.f;
    ot[1] = (f32x16)0.f;
    s16x8 pf[4];                      // P frags of tile t-1, live across iters

    unsigned short* vprev = Vbuf2;
    unsigned short* vcur  = Vbuf0;
    unsigned short* vnext = Vbuf1;

    const int NT = (L_ / 2) / 64;     // 16 tiles per half

    for (int kt = 0; kt < NT; ++kt) {
        __syncthreads();   // stage(kt) landed everywhere; old buffers free
        if (kt + 1 < NT) {
            unsigned short* kn = ((kt + 1) & 1) ? Kbuf1 : Kbuf0;
            gl_lds16(ks0 + (kt + 1) * 4096, kn + w4 * 512);
            gl_lds16(ks1 + (kt + 1) * 4096, kn + 2048 + w4 * 512);
            gl_lds16(vs0 + (kt + 1) * 64,   vnext + w4 * 512);
            gl_lds16(vs1 + (kt + 1) * 64,   vnext + 2048 + w4 * 512);
        }
        const unsigned short* __restrict__ Kl = (kt & 1) ? Kbuf1 : Kbuf0;

        // ---- QK(t): S^T = K·Q^T (log2-domain scores) ----
        f32x16 st[2];
        __builtin_amdgcn_s_setprio(1);
#pragma unroll
        for (int kv = 0; kv < 2; ++kv) {
            st[kv] = (f32x16)0.f;
            const int krow = kv * 32 + l31;
#pragma unroll
            for (int ks = 0; ks < 4; ++ks) {
                const s16x8 kf = *reinterpret_cast<const s16x8*>(
                    &Kl[(krow * 64 + ks * 16 + hh * 8) ^ ((krow & 7) << 3)]);
                st[kv] = __builtin_amdgcn_mfma_f32_32x32x16_bf16(kf, qfrag[ks], st[kv], 0, 0, 0);
            }
        }

        // ---- PV(t-1) (in flight during softmax(t)) ----
        if (kt) {
#pragma unroll
            for (int dt = 0; dt < 2; ++dt) {
                const int drow = dt * 32 + l31;
#pragma unroll
                for (int kc = 0; kc < 4; ++kc) {
                    const s16x8 vf = *reinterpret_cast<const s16x8*>(
                        &vprev[(drow * 64 + kc * 16 + hh * 8) ^ ((drow & 7) << 3)]);
                    ot[dt] = __builtin_amdgcn_mfma_f32_32x32x16_bf16(vf, pf[kc], ot[dt], 0, 0, 0);
                }
            }
        }
        __builtin_amdgcn_s_setprio(0);

        // ---- softmax(t): max3 tree + defer-max rescale + exp + sum + pack ----
        const float t0 = max3f(st[0][0],  st[0][1],  st[0][2]);
        const float t1 = max3f(st[0][3],  st[0][4],  st[0][5]);
        const float t2 = max3f(st[0][6],  st[0][7],  st[0][8]);
        const float t3 = max3f(st[0][9],  st[0][10], st[0][11]);
        const float t4 = max3f(st[0][12], st[0][13], st[0][14]);
        const float t5 = max3f(st[0][15], st[1][0],  st[1][1]);
        const float t6 = max3f(st[1][2],  st[1][3],  st[1][4]);
        const float t7 = max3f(st[1][5],  st[1][6],  st[1][7]);
        const float t8 = max3f(st[1][8],  st[1][9],  st[1][10]);
        const float t9 = max3f(st[1][11], st[1][12], st[1][13]);
        const float ta = fmaxf(st[1][14], st[1][15]);
        const float u0 = max3f(t0, t1, t2);
        const float u1 = max3f(t3, t4, t5);
        const float u2 = max3f(t6, t7, t8);
        const float u3 = fmaxf(t9, ta);
        float tmax = fmaxf(max3f(u0, u1, u2), u3);
        tmax = fmaxf(tmax, __shfl_xor(tmax, 32));

        if (!__all(tmax <= m_ + 8.f)) {       // first tile: m_=-inf -> taken
            const float newm = fmaxf(m_, tmax);
            const float corr = exp2a(m_ - newm);   // 0 on first tile
            lsum *= corr;
            ot[0] *= corr;
            ot[1] *= corr;
            m_ = newm;
        }

        // exp2 in place (<= 2^8 bound via defer-max)
#pragma unroll
        for (int kv = 0; kv < 2; ++kv)
#pragma unroll
            for (int i = 0; i < 16; ++i) st[kv][i] = exp2a(st[kv][i] - m_);

        // tree sum of 32 values (4 partials; overlapped by PV MFMAs above)
        {
            float s0 = 0.f, s1 = 0.f, s2 = 0.f, s3 = 0.f;
#pragma unroll
            for (int i = 0; i < 4; ++i) {
                s0 += st[0][i];      s1 += st[0][i + 4];
                s2 += st[0][i + 8];  s3 += st[0][i + 12];
                s0 += st[1][i];      s1 += st[1][i + 4];
                s2 += st[1][i + 8];  s3 += st[1][i + 12];
            }
            float ts = (s0 + s1) + (s2 + s3);
            ts += __shfl_xor(ts, 32);
            lsum += ts;
        }

        // pack P -> PV B-frags (cvt_pk + permlane32_swap)
#pragma unroll
        for (int kv = 0; kv < 2; ++kv) {
            unsigned int A0 = cvtpk(st[kv][0],  st[kv][1]),  B0 = cvtpk(st[kv][2],  st[kv][3]);
            unsigned int A1 = cvtpk(st[kv][4],  st[kv][5]),  B1 = cvtpk(st[kv][6],  st[kv][7]);
            unsigned int A2 = cvtpk(st[kv][8],  st[kv][9]),  B2 = cvtpk(st[kv][10], st[kv][11]);
            unsigned int A3 = cvtpk(st[kv][12], st[kv][13]), B3 = cvtpk(st[kv][14], st[kv][15]);
            swap32(A0, A1); swap32(B0, B1);
            swap32(A2, A3); swap32(B2, B3);
            u32x4 lo; lo[0] = A0; lo[1] = B0; lo[2] = A1; lo[3] = B1;
            u32x4 hi; hi[0] = A2; hi[1] = B2; hi[2] = A3; hi[3] = B3;
            pf[kv * 2 + 0] = __builtin_bit_cast(s16x8, lo);
            pf[kv * 2 + 1] = __builtin_bit_cast(s16x8, hi);
        }

        // rotate V ring
        unsigned short* tmp = vprev;
        vprev = vcur; vcur = vnext; vnext = tmp;
    }

    // ---- per-half pipeline epilogue: final PV ----
    __builtin_amdgcn_s_setprio(1);
#pragma unroll
    for (int dt = 0; dt < 2; ++dt) {
        const int drow = dt * 32 + l31;
#pragma unroll
        for (int kc = 0; kc < 4; ++kc) {
            const s16x8 vf = *reinterpret_cast<const s16x8*>(
                &vprev[(drow * 64 + kc * 16 + hh * 8) ^ ((drow & 7) << 3)]);
            ot[dt] = __builtin_amdgcn_mfma_f32_32x32x16_bf16(vf, pf[kc], ot[dt], 0, 0, 0);
        }
    }
    __builtin_amdgcn_s_setprio(0);

    // ---- split-K merge via LDS ----
    // Barrier FIRST: all waves past their last read of ST -> ST[1] provably
    // dead before half-1 overwrites it (the round-7 NaN race fix).
    __syncthreads();
    float* mrg = reinterpret_cast<float*>(&ST[1][0]);
    const int slot = ((w4 << 6) + lane) * 36;      // 36 floats/lane, 16B-aligned
    if (half == 1) {
        *reinterpret_cast<f32x16*>(&mrg[slot])      = ot[0];
        *reinterpret_cast<f32x16*>(&mrg[slot + 16]) = ot[1];
        mrg[slot + 32] = m_;
        mrg[slot + 33] = lsum;
    }
    __syncthreads();
    if (half == 0) {
        const f32x16 ob0 = *reinterpret_cast<const f32x16*>(&mrg[slot]);
        const f32x16 ob1 = *reinterpret_cast<const f32x16*>(&mrg[slot + 16]);
        const float mB = mrg[slot + 32];
        const float lB = mrg[slot + 33];
        const float mm = fmaxf(m_, mB);
        const float sA = exp2a(m_ - mm);
        const float sB = exp2a(mB - mm);
        const float inv = 1.f / (lsum * sA + lB * sB);
        ot[0] = ot[0] * sA + ob0 * sB;
        ot[1] = ot[1] * sA + ob1 * sB;

#pragma unroll
        for (int dt = 0; dt < 2; ++dt) {
#pragma unroll
            for (int r = 0; r < 4; ++r) {
                uint2 o;
                o.x = cvtpk(ot[dt][4 * r + 0] * inv, ot[dt][4 * r + 1] * inv);
                o.y = cvtpk(ot[dt][4 * r + 2] * inv, ot[dt][4 * r + 3] * inv);
                const size_t elem = ((size_t)n * L_ + qrow) * E_ + h * D_ + dt * 32 + r * 8 + hh * 4;
                *reinterpret_cast<uint2*>(AO + elem) = o;
            }
        }
    }
}

// ---------------------------------------------------------------------------
// Kernel 3: output projection via bf16 MFMA with Wo = Whi + Wlo split.
// ---------------------------------------------------------------------------
__global__ __launch_bounds__(256) void out_proj_kernel(
    const unsigned short* __restrict__ AO, const unsigned short* __restrict__ Whi,
    const unsigned short* __restrict__ Wlo, const float* __restrict__ bo,
    float* __restrict__ out)
{
    __shared__ __align__(16) unsigned short Adb[2][4096];
    __shared__ __align__(16) unsigned short Hdb[2][4096];
    __shared__ __align__(16) unsigned short Ldb[2][4096];

    const int tid = threadIdx.x;
    const int bid = blockIdx.x;
    const int mt = bid >> 3, nt = bid & 7;
    const int m0 = mt * 64, n0 = nt * 64;
    const int wave = tid >> 6, lane = tid & 63;
    const int ql = lane & 15, g = lane >> 4;

    const int G0 = wave * 64 + lane;
    const int G1 = G0 + 256;
    const int r0 = G0 >> 3, c0 = (G0 & 7) ^ (r0 & 7);
    const int r1 = G1 >> 3, c1 = (G1 & 7) ^ (r1 & 7);

    const unsigned short* as0 = AO + (size_t)(m0 + r0) * E_ + c0 * 8;
    const unsigned short* as1 = AO + (size_t)(m0 + r1) * E_ + c1 * 8;
    const unsigned short* hs0 = Whi + (size_t)(n0 + r0) * E_ + c0 * 8;
    const unsigned short* hs1 = Whi + (size_t)(n0 + r1) * E_ + c1 * 8;
    const unsigned short* ls0 = Wlo + (size_t)(n0 + r0) * E_ + c0 * 8;
    const unsigned short* ls1 = Wlo + (size_t)(n0 + r1) * E_ + c1 * 8;

    gl_lds16(as0, &Adb[0][wave * 512]);
    gl_lds16(as1, &Adb[0][2048 + wave * 512]);
    gl_lds16(hs0, &Hdb[0][wave * 512]);
    gl_lds16(hs1, &Hdb[0][2048 + wave * 512]);
    gl_lds16(ls0, &Ldb[0][wave * 512]);
    gl_lds16(ls1, &Ldb[0][2048 + wave * 512]);

    float bias[4];
#pragma unroll
    for (int t = 0; t < 4; ++t) bias[t] = bo[n0 + t * 16 + ql];

    f32x4 acc[4];
#pragma unroll
    for (int t = 0; t < 4; ++t) acc[t] = (f32x4){0.f, 0.f, 0.f, 0.f};

    const int arow = wave * 16 + ql;

    for (int kc = 0; kc < 8; ++kc) {
        const int b = kc & 1;
        __syncthreads();
        if (kc + 1 < 8) {
            const int nb = b ^ 1;
            const int ko = (kc + 1) * 64;
            gl_lds16(as0 + ko, &Adb[nb][wave * 512]);
            gl_lds16(as1 + ko, &Adb[nb][2048 + wave * 512]);
            gl_lds16(hs0 + ko, &Hdb[nb][wave * 512]);
            gl_lds16(hs1 + ko, &Hdb[nb][2048 + wave * 512]);
            gl_lds16(ls0 + ko, &Ldb[nb][wave * 512]);
            gl_lds16(ls1 + ko, &Ldb[nb][2048 + wave * 512]);
        }
        const unsigned short* __restrict__ Al = Adb[b];
        const unsigned short* __restrict__ Hl = Hdb[b];
        const unsigned short* __restrict__ Ll = Ldb[b];

        s16x8 af[2];
#pragma unroll
        for (int ks = 0; ks < 2; ++ks)
            af[ks] = *reinterpret_cast<const s16x8*>(
                &Al[(arow * 64 + ks * 32 + g * 8) ^ ((arow & 7) << 3)]);

        __builtin_amdgcn_s_setprio(1);
#pragma unroll
        for (int t = 0; t < 4; ++t) {
            const int wrow = t * 16 + ql;
#pragma unroll
            for (int ks = 0; ks < 2; ++ks) {
                const s16x8 bh = *reinterpret_cast<const s16x8*>(
                    &Hl[(wrow * 64 + ks * 32 + g * 8) ^ ((wrow & 7) << 3)]);
                acc[t] = __builtin_amdgcn_mfma_f32_16x16x32_bf16(af[ks], bh, acc[t], 0, 0, 0);
                const s16x8 bl = *reinterpret_cast<const s16x8*>(
                    &Ll[(wrow * 64 + ks * 32 + g * 8) ^ ((wrow & 7) << 3)]);
                acc[t] = __builtin_amdgcn_mfma_f32_16x16x32_bf16(af[ks], bl, acc[t], 0, 0, 0);
            }
        }
        __builtin_amdgcn_s_setprio(0);
    }

    // epilogue: D[m = m0+wave*16+g*4+r][n = n0+t*16+ql]
#pragma unroll
    for (int t = 0; t < 4; ++t) {
#pragma unroll
        for (int r = 0; r < 4; ++r) {
            out[(size_t)(m0 + wave * 16 + g * 4 + r) * E_ + n0 + t * 16 + ql] =
                acc[t][r] + bias[t];
        }
    }
}

// ---------------------------------------------------------------------------
extern "C" void kernel_launch(void* const* d_in, const int* in_sizes, int n_in,
                              void* d_out, int out_size, void* d_ws, size_t ws_size,
                              hipStream_t stream)
{
    const float* Q  = (const float*)d_in[0];
    const float* K  = (const float*)d_in[1];
    const float* V  = (const float*)d_in[2];
    const float* Wq = (const float*)d_in[3];
    const float* Wk = (const float*)d_in[4];
    const float* Wv = (const float*)d_in[5];
    const float* Wo = (const float*)d_in[6];
    const float* bo = (const float*)d_in[7];
    float* out = (float*)d_out;

    unsigned short* ws = (unsigned short*)d_ws;
    const size_t SZ = (size_t)N_ * H_ * L_ * D_;   // 4,194,304 elems
    unsigned short* Qp  = ws;
    unsigned short* Kp  = ws + SZ;
    unsigned short* Vt  = ws + 2 * SZ;
    unsigned short* AO  = ws + 3 * SZ;
    unsigned short* Whi = ws + 4 * SZ;
    unsigned short* Wlo = ws + 4 * SZ + 262144;

    qkv_proj_kernel<<<dim3(32, 32, 3), 256, 0, stream>>>(Q, K, V, Wq, Wk, Wv, Qp, Kp, Vt);
    wo_split_kernel<<<256, 256, 0, stream>>>(Wo, Whi, Wlo);
    attn_kernel<<<512, 512, 0, stream>>>(Qp, Kp, Vt, AO);
    out_proj_kernel<<<(8192 / 64) * (E_ / 64), 256, 0, stream>>>(AO, Whi, Wlo, bo, out);
}

// Round 12
// 92.392 us; speedup vs baseline: 1.5974x; 1.2358x over previous
//
#include <hip/hip_runtime.h>
#include <math.h>

#define N_ 4
#define L_ 2048
#define E_ 512
#define H_ 8
#define D_ 64

// SCALE = 1/sqrt(512) (reference scales by sqrt(embed_size));
// QSCALE = SCALE * log2(e): scores come out of QK^T in log2 domain.
#define QSCALE 0.06375871588055019f

typedef short s16x8 __attribute__((ext_vector_type(8)));
typedef float f32x4 __attribute__((ext_vector_type(4)));
typedef float f32x16 __attribute__((ext_vector_type(16)));
typedef unsigned int u32x4 __attribute__((ext_vector_type(4)));

typedef const __attribute__((address_space(1))) unsigned int ga_u32;
typedef __attribute__((address_space(3))) unsigned int lds_u32;

// async 16B global->LDS (dest = wave-uniform base + lane*16, linear)
__device__ __forceinline__ void gl_lds16(const unsigned short* g, unsigned short* l) {
    __builtin_amdgcn_global_load_lds((ga_u32*)g, (lds_u32*)l, 16, 0, 0);
}
__device__ __forceinline__ float exp2a(float x) {
    float r; asm("v_exp_f32 %0, %1" : "=v"(r) : "v"(x)); return r;
}
__device__ __forceinline__ unsigned int cvtpk(float lo, float hi) {
    unsigned int r; asm("v_cvt_pk_bf16_f32 %0, %1, %2" : "=v"(r) : "v"(lo), "v"(hi)); return r;
}
// v_permlane32_swap_b32 a, b: a<-{a_lo, b_lo}, b<-{a_hi, b_hi} (lane halves)
__device__ __forceinline__ void swap32(unsigned int& a, unsigned int& b) {
    asm volatile("v_permlane32_swap_b32 %0, %1" : "+v"(a), "+v"(b));
}
__device__ __forceinline__ float max3f(float a, float b, float c) {
    return fmaxf(fmaxf(a, b), c);   // clang fuses to v_max3_f32
}
__device__ __forceinline__ unsigned short f2bf(float x) {
    unsigned int u = __builtin_bit_cast(unsigned int, x);
    u = (u + 0x7FFFu + ((u >> 16) & 1u)) >> 16;   // RNE
    return (unsigned short)u;
}
__device__ __forceinline__ float bflo(unsigned int w) {
    return __builtin_bit_cast(float, w << 16);
}
__device__ __forceinline__ float bfhi(unsigned int w) {
    return __builtin_bit_cast(float, w & 0xFFFF0000u);
}

// ---------------------------------------------------------------------------
// Kernel 0: split Wo (fp32 512x512) into bf16 hi + bf16 residual lo.
// ---------------------------------------------------------------------------
__global__ __launch_bounds__(256) void wo_split_kernel(
    const float* __restrict__ Wo, unsigned short* __restrict__ Whi,
    unsigned short* __restrict__ Wlo)
{
    const int i = blockIdx.x * 256 + threadIdx.x;
    const float4 w = reinterpret_cast<const float4*>(Wo)[i];
    const unsigned int hxy = cvtpk(w.x, w.y);
    const unsigned int hzw = cvtpk(w.z, w.w);
    const unsigned int lxy = cvtpk(w.x - bflo(hxy), w.y - bfhi(hxy));
    const unsigned int lzw = cvtpk(w.z - bflo(hzw), w.w - bfhi(hzw));
    uint2 hh; hh.x = hxy; hh.y = hzw;
    uint2 ll; ll.x = lxy; ll.y = lzw;
    reinterpret_cast<uint2*>(Whi)[i] = hh;
    reinterpret_cast<uint2*>(Wlo)[i] = ll;
}

// ---------------------------------------------------------------------------
// Kernel 1 (THIS ROUND'S ONLY DELTA): per-head QKV projection via bf16 MFMA.
// X tile converted to bf16 (RNE) in LDS; W (64x64 fp32) split in-block into
// bf16 hi+lo tiles (accuracy-preserving). 16x16x32 MFMA, out_proj operand
// pattern. m<2 (Q/K): D[l][e] = mfma(xf, wf). m=2 (V): D[e][l] = mfma(wf, xf)
// -> transposed Vt layout for free. Q: QSCALE folded into W before split.
// Results restaged via Yl for coalesced 32B stores.
// ---------------------------------------------------------------------------
__global__ __launch_bounds__(256) void qkv_proj_kernel(
    const float* __restrict__ Q, const float* __restrict__ K, const float* __restrict__ V,
    const float* __restrict__ Wq, const float* __restrict__ Wk, const float* __restrict__ Wv,
    unsigned short* __restrict__ Qp, unsigned short* __restrict__ Kp,
    unsigned short* __restrict__ Vt)
{
    __shared__ __align__(16) unsigned short Xl[4096];     // bf16, swizzled
    __shared__ __align__(16) unsigned short Whl[4096];    // W hi, swizzled
    __shared__ __align__(16) unsigned short Wll[4096];    // W lo, swizzled
    __shared__ __align__(16) unsigned short Yl[64][72];

    const int tid = threadIdx.x;
    const int lt = blockIdx.x;
    const int nh = blockIdx.y;
    const int m  = blockIdx.z;       // 0:Q 1:K 2:V
    const int n = nh >> 3, h = nh & 7;
    const int l0 = lt * 64;

    const float* __restrict__ in = (m == 0) ? Q : (m == 1) ? K : V;
    const float* __restrict__ W  = (m == 0) ? Wq : (m == 1) ? Wk : Wv;

    // ---- load X row-chunk + W row-chunk fp32 -> convert -> bf16 LDS ----
    const int xr = tid >> 2;              // 0..63
    const int xc = (tid & 3) * 16;        // col base
    {
        const float* xs = in + (size_t)(n * L_ + l0 + xr) * E_ + h * D_ + xc;
        float4 a = reinterpret_cast<const float4*>(xs)[0];
        float4 b = reinterpret_cast<const float4*>(xs)[1];
        float4 c = reinterpret_cast<const float4*>(xs)[2];
        float4 d = reinterpret_cast<const float4*>(xs)[3];
        u32x4 w0, w1;
        w0[0] = cvtpk(a.x, a.y); w0[1] = cvtpk(a.z, a.w);
        w0[2] = cvtpk(b.x, b.y); w0[3] = cvtpk(b.z, b.w);
        w1[0] = cvtpk(c.x, c.y); w1[1] = cvtpk(c.z, c.w);
        w1[2] = cvtpk(d.x, d.y); w1[3] = cvtpk(d.z, d.w);
        const int base  = (xr * 64 + xc) ^ ((xr & 7) << 3);
        const int base2 = (xr * 64 + xc + 8) ^ ((xr & 7) << 3);
        *reinterpret_cast<u32x4*>(&Xl[base])  = w0;
        *reinterpret_cast<u32x4*>(&Xl[base2]) = w1;

        const float* wsrc = W + (size_t)xr * D_ + xc;
        float wv[16];
#pragma unroll
        for (int i = 0; i < 4; ++i) {
            const float4 t = reinterpret_cast<const float4*>(wsrc)[i];
            wv[i * 4 + 0] = t.x; wv[i * 4 + 1] = t.y;
            wv[i * 4 + 2] = t.z; wv[i * 4 + 3] = t.w;
        }
        if (m == 0) {
#pragma unroll
            for (int i = 0; i < 16; ++i) wv[i] *= QSCALE;
        }
        u32x4 hi0, hi1, lo0, lo1;
#pragma unroll
        for (int i = 0; i < 4; ++i) {
            const unsigned int hw = cvtpk(wv[2 * i], wv[2 * i + 1]);
            hi0[i] = hw;
            lo0[i] = cvtpk(wv[2 * i] - bflo(hw), wv[2 * i + 1] - bfhi(hw));
        }
#pragma unroll
        for (int i = 0; i < 4; ++i) {
            const unsigned int hw = cvtpk(wv[8 + 2 * i], wv[8 + 2 * i + 1]);
            hi1[i] = hw;
            lo1[i] = cvtpk(wv[8 + 2 * i] - bflo(hw), wv[8 + 2 * i + 1] - bfhi(hw));
        }
        *reinterpret_cast<u32x4*>(&Whl[base])  = hi0;
        *reinterpret_cast<u32x4*>(&Whl[base2]) = hi1;
        *reinterpret_cast<u32x4*>(&Wll[base])  = lo0;
        *reinterpret_cast<u32x4*>(&Wll[base2]) = lo1;
    }
    __syncthreads();

    const int wave = tid >> 6, lane = tid & 63;
    const int ql = lane & 15, g = lane >> 4;
    const int arow = wave * 16 + ql;

    f32x4 acc[4];
#pragma unroll
    for (int t = 0; t < 4; ++t) acc[t] = (f32x4){0.f, 0.f, 0.f, 0.f};

    if (m < 2) {
        // D[l][e] = mfma(A=X row l, B=W row e)   (out_proj-verified pattern)
        s16x8 xf[2];
#pragma unroll
        for (int ks = 0; ks < 2; ++ks)
            xf[ks] = *reinterpret_cast<const s16x8*>(
                &Xl[(arow * 64 + ks * 32 + g * 8) ^ ((arow & 7) << 3)]);
#pragma unroll
        for (int t = 0; t < 4; ++t) {
            const int wrow = t * 16 + ql;
#pragma unroll
            for (int ks = 0; ks < 2; ++ks) {
                const s16x8 bh = *reinterpret_cast<const s16x8*>(
                    &Whl[(wrow * 64 + ks * 32 + g * 8) ^ ((wrow & 7) << 3)]);
                acc[t] = __builtin_amdgcn_mfma_f32_16x16x32_bf16(xf[ks], bh, acc[t], 0, 0, 0);
                const s16x8 bl = *reinterpret_cast<const s16x8*>(
                    &Wll[(wrow * 64 + ks * 32 + g * 8) ^ ((wrow & 7) << 3)]);
                acc[t] = __builtin_amdgcn_mfma_f32_16x16x32_bf16(xf[ks], bl, acc[t], 0, 0, 0);
            }
        }
    } else {
        // D[e][l] = mfma(A=W row e, B=X row l)  -> transposed for Vt
        s16x8 whf[2], wlf[2];
#pragma unroll
        for (int ks = 0; ks < 2; ++ks) {
            whf[ks] = *reinterpret_cast<const s16x8*>(
                &Whl[(arow * 64 + ks * 32 + g * 8) ^ ((arow & 7) << 3)]);
            wlf[ks] = *reinterpret_cast<const s16x8*>(
                &Wll[(arow * 64 + ks * 32 + g * 8) ^ ((arow & 7) << 3)]);
        }
#pragma unroll
        for (int t = 0; t < 4; ++t) {
            const int xrow = t * 16 + ql;
#pragma unroll
            for (int ks = 0; ks < 2; ++ks) {
                const s16x8 bx = *reinterpret_cast<const s16x8*>(
                    &Xl[(xrow * 64 + ks * 32 + g * 8) ^ ((xrow & 7) << 3)]);
                acc[t] = __builtin_amdgcn_mfma_f32_16x16x32_bf16(whf[ks], bx, acc[t], 0, 0, 0);
                acc[t] = __builtin_amdgcn_mfma_f32_16x16x32_bf16(wlf[ks], bx, acc[t], 0, 0, 0);
            }
        }
    }

    // ---- restage D into Yl (row = A-row, col = B-row; same for both m) ----
#pragma unroll
    for (int t = 0; t < 4; ++t)
#pragma unroll
        for (int r = 0; r < 4; ++r)
            Yl[wave * 16 + g * 4 + r][t * 16 + ql] = f2bf(acc[t][r]);
    __syncthreads();

    // ---- coalesced store: thread -> 32B (16 bf16) ----
    const int orow = tid >> 2;
    const int oc = (tid & 3) * 16;
    const uint4 v0 = *reinterpret_cast<const uint4*>(&Yl[orow][oc]);
    const uint4 v1 = *reinterpret_cast<const uint4*>(&Yl[orow][oc + 8]);
    unsigned short* dst;
    if (m == 0)      dst = Qp + ((size_t)nh * L_ + l0 + orow) * D_ + oc;
    else if (m == 1) dst = Kp + ((size_t)nh * L_ + l0 + orow) * D_ + oc;
    else             dst = Vt + ((size_t)nh * D_ + orow) * L_ + l0 + oc;
    *reinterpret_cast<uint4*>(dst) = v0;
    *reinterpret_cast<uint4*>(dst + 8) = v1;
}

// ---------------------------------------------------------------------------
// Kernel 2: bf16 MFMA flash attention — EXACT round-10 version (passed,
// 59.9us, VGPR=72, no spill). 32x32x16, in-register P, software pipelined,
// in-block split-K, V triple-buffer, 80KB LDS, merge at ST[1] (barrier-first).
// ---------------------------------------------------------------------------
__global__ __launch_bounds__(512, 2) void attn_kernel(
    const unsigned short* __restrict__ Qp, const unsigned short* __restrict__ Kp,
    const unsigned short* __restrict__ Vt, unsigned short* __restrict__ AO)
{
    // [half][buf]: bufs 0-1 = K double-buffer, 2-4 = V triple-buffer
    __shared__ __align__(16) unsigned short ST[2][5 * 4096];

    const int tid = threadIdx.x;
    const int phys = blockIdx.x;
    const int bid = (phys & 7) * 64 + (phys >> 3);   // bijective: 512 = 8*64
    const int qt = bid & 15;
    const int nh = bid >> 4;          // 4 heads per XCD -> K/V L2-resident
    const int n = nh >> 3, h = nh & 7;
    const int q0 = qt * 128;
    const int wave = tid >> 6;
    const int half = wave >> 2;       // key-range half
    const int w4 = wave & 3;          // wave-in-half: owns q rows w4*32..+31
    const int lane = tid & 63;
    const int l31 = lane & 31;
    const int hh  = lane >> 5;

    const unsigned short* __restrict__ Qb = Qp + (size_t)nh * (L_ * D_);
    const unsigned short* __restrict__ Kb = Kp + (size_t)nh * (L_ * D_);
    const unsigned short* __restrict__ Vb = Vt + (size_t)nh * (D_ * L_);

    unsigned short* const Kbuf0 = &ST[half][0];
    unsigned short* const Kbuf1 = &ST[half][4096];
    unsigned short* const Vbuf0 = &ST[half][2 * 4096];
    unsigned short* const Vbuf1 = &ST[half][3 * 4096];
    unsigned short* const Vbuf2 = &ST[half][4 * 4096];

    // staging geometry: granule G -> global (row=G>>3, c8=(G&7)^(row&7))
    const int G0 = w4 * 64 + lane;
    const int G1 = G0 + 256;
    const int r0 = G0 >> 3, c0 = (G0 & 7) ^ (r0 & 7);
    const int r1 = G1 >> 3, c1 = (G1 & 7) ^ (r1 & 7);

    const int kbase = half * 1024;    // first key of this half
    const unsigned short* ks0 = Kb + (size_t)(kbase + r0) * 64 + c0 * 8;
    const unsigned short* ks1 = Kb + (size_t)(kbase + r1) * 64 + c1 * 8;
    const unsigned short* vs0 = Vb + (size_t)r0 * L_ + kbase + c0 * 8;
    const unsigned short* vs1 = Vb + (size_t)r1 * L_ + kbase + c1 * 8;

    // prologue: stage kt=0
    gl_lds16(ks0, Kbuf0 + w4 * 512);
    gl_lds16(ks1, Kbuf0 + 2048 + w4 * 512);
    gl_lds16(vs0, Vbuf0 + w4 * 512);
    gl_lds16(vs1, Vbuf0 + 2048 + w4 * 512);

    // Q fragments straight to registers: B[k=d][col=q], q=q0+w4*32+l31
    const int qrow = q0 + w4 * 32 + l31;
    s16x8 qfrag[4];
#pragma unroll
    for (int ks = 0; ks < 4; ++ks)
        qfrag[ks] = *reinterpret_cast<const s16x8*>(
            Qb + (size_t)qrow * D_ + ks * 16 + hh * 8);

    float m_ = -INFINITY;
    float lsum = 0.f;
    f32x16 ot[2];
    ot[0] = (f32x16)0.f;
    ot[1] = (f32x16)0.f;
    s16x8 pf[4];                      // P frags of tile t-1, live across iters

    unsigned short* vprev = Vbuf2;
    unsigned short* vcur  = Vbuf0;
    unsigned short* vnext = Vbuf1;

    const int NT = (L_ / 2) / 64;     // 16 tiles per half

    for (int kt = 0; kt < NT; ++kt) {
        __syncthreads();   // stage(kt) landed everywhere; old buffers free
        if (kt + 1 < NT) {
            unsigned short* kn = ((kt + 1) & 1) ? Kbuf1 : Kbuf0;
            gl_lds16(ks0 + (kt + 1) * 4096, kn + w4 * 512);
            gl_lds16(ks1 + (kt + 1) * 4096, kn + 2048 + w4 * 512);
            gl_lds16(vs0 + (kt + 1) * 64,   vnext + w4 * 512);
            gl_lds16(vs1 + (kt + 1) * 64,   vnext + 2048 + w4 * 512);
        }
        const unsigned short* __restrict__ Kl = (kt & 1) ? Kbuf1 : Kbuf0;

        // ---- QK(t): S^T = K·Q^T (log2-domain scores) ----
        f32x16 st[2];
        __builtin_amdgcn_s_setprio(1);
#pragma unroll
        for (int kv = 0; kv < 2; ++kv) {
            st[kv] = (f32x16)0.f;
            const int krow = kv * 32 + l31;
#pragma unroll
            for (int ks = 0; ks < 4; ++ks) {
                const s16x8 kf = *reinterpret_cast<const s16x8*>(
                    &Kl[(krow * 64 + ks * 16 + hh * 8) ^ ((krow & 7) << 3)]);
                st[kv] = __builtin_amdgcn_mfma_f32_32x32x16_bf16(kf, qfrag[ks], st[kv], 0, 0, 0);
            }
        }

        // ---- PV(t-1) (in flight during softmax(t)) ----
        if (kt) {
#pragma unroll
            for (int dt = 0; dt < 2; ++dt) {
                const int drow = dt * 32 + l31;
#pragma unroll
                for (int kc = 0; kc < 4; ++kc) {
                    const s16x8 vf = *reinterpret_cast<const s16x8*>(
                        &vprev[(drow * 64 + kc * 16 + hh * 8) ^ ((drow & 7) << 3)]);
                    ot[dt] = __builtin_amdgcn_mfma_f32_32x32x16_bf16(vf, pf[kc], ot[dt], 0, 0, 0);
                }
            }
        }
        __builtin_amdgcn_s_setprio(0);

        // ---- softmax(t): max3 tree + defer-max rescale + exp + sum + pack ----
        const float t0 = max3f(st[0][0],  st[0][1],  st[0][2]);
        const float t1 = max3f(st[0][3],  st[0][4],  st[0][5]);
        const float t2 = max3f(st[0][6],  st[0][7],  st[0][8]);
        const float t3 = max3f(st[0][9],  st[0][10], st[0][11]);
        const float t4 = max3f(st[0][12], st[0][13], st[0][14]);
        const float t5 = max3f(st[0][15], st[1][0],  st[1][1]);
        const float t6 = max3f(st[1][2],  st[1][3],  st[1][4]);
        const float t7 = max3f(st[1][5],  st[1][6],  st[1][7]);
        const float t8 = max3f(st[1][8],  st[1][9],  st[1][10]);
        const float t9 = max3f(st[1][11], st[1][12], st[1][13]);
        const float ta = fmaxf(st[1][14], st[1][15]);
        const float u0 = max3f(t0, t1, t2);
        const float u1 = max3f(t3, t4, t5);
        const float u2 = max3f(t6, t7, t8);
        const float u3 = fmaxf(t9, ta);
        float tmax = fmaxf(max3f(u0, u1, u2), u3);
        tmax = fmaxf(tmax, __shfl_xor(tmax, 32));

        if (!__all(tmax <= m_ + 8.f)) {       // first tile: m_=-inf -> taken
            const float newm = fmaxf(m_, tmax);
            const float corr = exp2a(m_ - newm);   // 0 on first tile
            lsum *= corr;
            ot[0] *= corr;
            ot[1] *= corr;
            m_ = newm;
        }

        // exp2 in place (<= 2^8 bound via defer-max)
#pragma unroll
        for (int kv = 0; kv < 2; ++kv)
#pragma unroll
            for (int i = 0; i < 16; ++i) st[kv][i] = exp2a(st[kv][i] - m_);

        // tree sum of 32 values (overlapped by the PV MFMAs above)
        {
            float s0 = 0.f, s1 = 0.f, s2 = 0.f, s3 = 0.f;
#pragma unroll
            for (int i = 0; i < 4; ++i) {
                s0 += st[0][i];      s1 += st[0][i + 4];
                s2 += st[0][i + 8];  s3 += st[0][i + 12];
                s0 += st[1][i];      s1 += st[1][i + 4];
                s2 += st[1][i + 8];  s3 += st[1][i + 12];
            }
            float ts = (s0 + s1) + (s2 + s3);
            ts += __shfl_xor(ts, 32);
            lsum += ts;
        }

        // pack P -> PV B-frags (cvt_pk + permlane32_swap)
#pragma unroll
        for (int kv = 0; kv < 2; ++kv) {
            unsigned int A0 = cvtpk(st[kv][0],  st[kv][1]),  B0 = cvtpk(st[kv][2],  st[kv][3]);
            unsigned int A1 = cvtpk(st[kv][4],  st[kv][5]),  B1 = cvtpk(st[kv][6],  st[kv][7]);
            unsigned int A2 = cvtpk(st[kv][8],  st[kv][9]),  B2 = cvtpk(st[kv][10], st[kv][11]);
            unsigned int A3 = cvtpk(st[kv][12], st[kv][13]), B3 = cvtpk(st[kv][14], st[kv][15]);
            swap32(A0, A1); swap32(B0, B1);
            swap32(A2, A3); swap32(B2, B3);
            u32x4 lo; lo[0] = A0; lo[1] = B0; lo[2] = A1; lo[3] = B1;
            u32x4 hi; hi[0] = A2; hi[1] = B2; hi[2] = A3; hi[3] = B3;
            pf[kv * 2 + 0] = __builtin_bit_cast(s16x8, lo);
            pf[kv * 2 + 1] = __builtin_bit_cast(s16x8, hi);
        }

        // rotate V ring
        unsigned short* tmp = vprev;
        vprev = vcur; vcur = vnext; vnext = tmp;
    }

    // ---- per-half pipeline epilogue: final PV ----
    __builtin_amdgcn_s_setprio(1);
#pragma unroll
    for (int dt = 0; dt < 2; ++dt) {
        const int drow = dt * 32 + l31;
#pragma unroll
        for (int kc = 0; kc < 4; ++kc) {
            const s16x8 vf = *reinterpret_cast<const s16x8*>(
                &vprev[(drow * 64 + kc * 16 + hh * 8) ^ ((drow & 7) << 3)]);
            ot[dt] = __builtin_amdgcn_mfma_f32_32x32x16_bf16(vf, pf[kc], ot[dt], 0, 0, 0);
        }
    }
    __builtin_amdgcn_s_setprio(0);

    // ---- split-K merge via LDS ----
    // Barrier FIRST: all waves past their last read of ST -> ST[1] provably
    // dead before half-1 overwrites it (the round-7 NaN race fix).
    __syncthreads();
    float* mrg = reinterpret_cast<float*>(&ST[1][0]);
    const int slot = ((w4 << 6) + lane) * 36;      // 36 floats/lane, 16B-aligned
    if (half == 1) {
        *reinterpret_cast<f32x16*>(&mrg[slot])      = ot[0];
        *reinterpret_cast<f32x16*>(&mrg[slot + 16]) = ot[1];
        mrg[slot + 32] = m_;
        mrg[slot + 33] = lsum;
    }
    __syncthreads();
    if (half == 0) {
        const f32x16 ob0 = *reinterpret_cast<const f32x16*>(&mrg[slot]);
        const f32x16 ob1 = *reinterpret_cast<const f32x16*>(&mrg[slot + 16]);
        const float mB = mrg[slot + 32];
        const float lB = mrg[slot + 33];
        const float mm = fmaxf(m_, mB);
        const float sA = exp2a(m_ - mm);
        const float sB = exp2a(mB - mm);
        const float inv = 1.f / (lsum * sA + lB * sB);
        ot[0] = ot[0] * sA + ob0 * sB;
        ot[1] = ot[1] * sA + ob1 * sB;

#pragma unroll
        for (int dt = 0; dt < 2; ++dt) {
#pragma unroll
            for (int r = 0; r < 4; ++r) {
                uint2 o;
                o.x = cvtpk(ot[dt][4 * r + 0] * inv, ot[dt][4 * r + 1] * inv);
                o.y = cvtpk(ot[dt][4 * r + 2] * inv, ot[dt][4 * r + 3] * inv);
                const size_t elem = ((size_t)n * L_ + qrow) * E_ + h * D_ + dt * 32 + r * 8 + hh * 4;
                *reinterpret_cast<uint2*>(AO + elem) = o;
            }
        }
    }
}

// ---------------------------------------------------------------------------
// Kernel 3: output projection via bf16 MFMA with Wo = Whi + Wlo split.
// ---------------------------------------------------------------------------
__global__ __launch_bounds__(256) void out_proj_kernel(
    const unsigned short* __restrict__ AO, const unsigned short* __restrict__ Whi,
    const unsigned short* __restrict__ Wlo, const float* __restrict__ bo,
    float* __restrict__ out)
{
    __shared__ __align__(16) unsigned short Adb[2][4096];
    __shared__ __align__(16) unsigned short Hdb[2][4096];
    __shared__ __align__(16) unsigned short Ldb[2][4096];

    const int tid = threadIdx.x;
    const int bid = blockIdx.x;
    const int mt = bid >> 3, nt = bid & 7;
    const int m0 = mt * 64, n0 = nt * 64;
    const int wave = tid >> 6, lane = tid & 63;
    const int ql = lane & 15, g = lane >> 4;

    const int G0 = wave * 64 + lane;
    const int G1 = G0 + 256;
    const int r0 = G0 >> 3, c0 = (G0 & 7) ^ (r0 & 7);
    const int r1 = G1 >> 3, c1 = (G1 & 7) ^ (r1 & 7);

    const unsigned short* as0 = AO + (size_t)(m0 + r0) * E_ + c0 * 8;
    const unsigned short* as1 = AO + (size_t)(m0 + r1) * E_ + c1 * 8;
    const unsigned short* hs0 = Whi + (size_t)(n0 + r0) * E_ + c0 * 8;
    const unsigned short* hs1 = Whi + (size_t)(n0 + r1) * E_ + c1 * 8;
    const unsigned short* ls0 = Wlo + (size_t)(n0 + r0) * E_ + c0 * 8;
    const unsigned short* ls1 = Wlo + (size_t)(n0 + r1) * E_ + c1 * 8;

    gl_lds16(as0, &Adb[0][wave * 512]);
    gl_lds16(as1, &Adb[0][2048 + wave * 512]);
    gl_lds16(hs0, &Hdb[0][wave * 512]);
    gl_lds16(hs1, &Hdb[0][2048 + wave * 512]);
    gl_lds16(ls0, &Ldb[0][wave * 512]);
    gl_lds16(ls1, &Ldb[0][2048 + wave * 512]);

    float bias[4];
#pragma unroll
    for (int t = 0; t < 4; ++t) bias[t] = bo[n0 + t * 16 + ql];

    f32x4 acc[4];
#pragma unroll
    for (int t = 0; t < 4; ++t) acc[t] = (f32x4){0.f, 0.f, 0.f, 0.f};

    const int arow = wave * 16 + ql;

    for (int kc = 0; kc < 8; ++kc) {
        const int b = kc & 1;
        __syncthreads();
        if (kc + 1 < 8) {
            const int nb = b ^ 1;
            const int ko = (kc + 1) * 64;
            gl_lds16(as0 + ko, &Adb[nb][wave * 512]);
            gl_lds16(as1 + ko, &Adb[nb][2048 + wave * 512]);
            gl_lds16(hs0 + ko, &Hdb[nb][wave * 512]);
            gl_lds16(hs1 + ko, &Hdb[nb][2048 + wave * 512]);
            gl_lds16(ls0 + ko, &Ldb[nb][wave * 512]);
            gl_lds16(ls1 + ko, &Ldb[nb][2048 + wave * 512]);
        }
        const unsigned short* __restrict__ Al = Adb[b];
        const unsigned short* __restrict__ Hl = Hdb[b];
        const unsigned short* __restrict__ Ll = Ldb[b];

        s16x8 af[2];
#pragma unroll
        for (int ks = 0; ks < 2; ++ks)
            af[ks] = *reinterpret_cast<const s16x8*>(
                &Al[(arow * 64 + ks * 32 + g * 8) ^ ((arow & 7) << 3)]);

        __builtin_amdgcn_s_setprio(1);
#pragma unroll
        for (int t = 0; t < 4; ++t) {
            const int wrow = t * 16 + ql;
#pragma unroll
            for (int ks = 0; ks < 2; ++ks) {
                const s16x8 bh = *reinterpret_cast<const s16x8*>(
                    &Hl[(wrow * 64 + ks * 32 + g * 8) ^ ((wrow & 7) << 3)]);
                acc[t] = __builtin_amdgcn_mfma_f32_16x16x32_bf16(af[ks], bh, acc[t], 0, 0, 0);
                const s16x8 bl = *reinterpret_cast<const s16x8*>(
                    &Ll[(wrow * 64 + ks * 32 + g * 8) ^ ((wrow & 7) << 3)]);
                acc[t] = __builtin_amdgcn_mfma_f32_16x16x32_bf16(af[ks], bl, acc[t], 0, 0, 0);
            }
        }
        __builtin_amdgcn_s_setprio(0);
    }

    // epilogue: D[m = m0+wave*16+g*4+r][n = n0+t*16+ql]
#pragma unroll
    for (int t = 0; t < 4; ++t) {
#pragma unroll
        for (int r = 0; r < 4; ++r) {
            out[(size_t)(m0 + wave * 16 + g * 4 + r) * E_ + n0 + t * 16 + ql] =
                acc[t][r] + bias[t];
        }
    }
}

// ---------------------------------------------------------------------------
extern "C" void kernel_launch(void* const* d_in, const int* in_sizes, int n_in,
                              void* d_out, int out_size, void* d_ws, size_t ws_size,
                              hipStream_t stream)
{
    const float* Q  = (const float*)d_in[0];
    const float* K  = (const float*)d_in[1];
    const float* V  = (const float*)d_in[2];
    const float* Wq = (const float*)d_in[3];
    const float* Wk = (const float*)d_in[4];
    const float* Wv = (const float*)d_in[5];
    const float* Wo = (const float*)d_in[6];
    const float* bo = (const float*)d_in[7];
    float* out = (float*)d_out;

    unsigned short* ws = (unsigned short*)d_ws;
    const size_t SZ = (size_t)N_ * H_ * L_ * D_;   // 4,194,304 elems
    unsigned short* Qp  = ws;
    unsigned short* Kp  = ws + SZ;
    unsigned short* Vt  = ws + 2 * SZ;
    unsigned short* AO  = ws + 3 * SZ;
    unsigned short* Whi = ws + 4 * SZ;
    unsigned short* Wlo = ws + 4 * SZ + 262144;

    qkv_proj_kernel<<<dim3(32, 32, 3), 256, 0, stream>>>(Q, K, V, Wq, Wk, Wv, Qp, Kp, Vt);
    wo_split_kernel<<<256, 256, 0, stream>>>(Wo, Whi, Wlo);
    attn_kernel<<<512, 512, 0, stream>>>(Qp, Kp, Vt, AO);
    out_proj_kernel<<<(8192 / 64) * (E_ / 64), 256, 0, stream>>>(AO, Whi, Wlo, bo, out);
}